// Round 2
// baseline (374.533 us; speedup 1.0000x reference)
//
#include <hip/hip_runtime.h>
#include <hip/hip_bf16.h>

// ---------------- problem constants ----------------
constexpr int Bn = 4, Sn = 1024, En = 768, Hn = 12, Fn = 3072, Dn = 64;
constexpr int Mn = Bn * Sn;  // 4096 rows

typedef __attribute__((ext_vector_type(8))) short bf16x8;
typedef __attribute__((ext_vector_type(4))) float f32x4;

__device__ __forceinline__ short f2bs(float f) {
  unsigned u = __builtin_bit_cast(unsigned, f);
  unsigned r = (u + 0x7fffu + ((u >> 16) & 1u)) >> 16;  // RNE
  return (short)(r & 0xffffu);
}

__device__ __forceinline__ void gload16(const void* g, void* l) {
  __builtin_amdgcn_global_load_lds(
      (const __attribute__((address_space(1))) void*)g,
      (__attribute__((address_space(3))) void*)l, 16, 0, 0);
}

// ---------------- prep kernels ----------------
__global__ __launch_bounds__(256) void cvt_f32_bf16(
    const float* __restrict__ in, short* __restrict__ out, int n) {
  int i = (blockIdx.x * 256 + threadIdx.x) * 4;
  if (i >= n) return;
  float4 f = *(const float4*)(in + i);
  short4 o;
  o.x = f2bs(f.x); o.y = f2bs(f.y); o.z = f2bs(f.z); o.w = f2bs(f.w);
  *(short4*)(out + i) = o;
}

// W [K][N] f32 -> Wt [N][K] bf16
__global__ __launch_bounds__(256) void transpose_w(
    const float* __restrict__ W, short* __restrict__ Wt, int K, int N) {
  __shared__ float t[32][33];
  int bx = blockIdx.x * 32, by = blockIdx.y * 32;
  int tx = threadIdx.x, ty = threadIdx.y;
#pragma unroll
  for (int i = ty; i < 32; i += 8)
    t[i][tx] = W[(size_t)(by + i) * N + bx + tx];
  __syncthreads();
#pragma unroll
  for (int i = ty; i < 32; i += 8)
    Wt[(size_t)(bx + i) * K + by + tx] = f2bs(t[tx][i]);
}

// ---------------- GEMM: C[M,N] = A[M,K](bf16) * Bt[N,K]^T(bf16) ----------------
// MODE 0: Cf = raw f32           MODE 1: QKV scatter (+bias) -> Qo/Ko/Vto bf16
// MODE 2: Cb = bf16 gelu(acc + bias0)
template <int MODE>
__global__ __launch_bounds__(256, 2) void gemm_bt(
    const short* __restrict__ A, const short* __restrict__ Bt,
    int M, int N, int K,
    float* __restrict__ Cf, short* __restrict__ Cb,
    const float* __restrict__ bias0, const float* __restrict__ bias1,
    const float* __restrict__ bias2,
    short* __restrict__ Qo, short* __restrict__ Ko, short* __restrict__ Vto) {
  __shared__ short Asm[128 * 64];
  __shared__ short Bsm[128 * 64];
  const int tid = threadIdx.x, wv = tid >> 6, ln = tid & 63;
  const int m0 = blockIdx.y * 128, n0 = blockIdx.x * 128;
  const int wm = (wv >> 1) * 64, wn = (wv & 1) * 64;
  f32x4 acc[4][4] = {};

  for (int k0 = 0; k0 < K; k0 += 64) {
    // stage 2x 16KB tiles: pre-swizzled global source -> linear LDS dest
    // (read below applies the same XOR; rule #21 both-sides involution)
#pragma unroll
    for (int i = 0; i < 4; ++i) {
      int off = wv * 4096 + i * 1024 + ln * 16;  // byte offset in tile
      int r = off >> 7, sl = (off >> 4) & 7, ss = sl ^ (r & 7);
      gload16(A + (size_t)(m0 + r) * K + k0 + ss * 8,
              (char*)Asm + wv * 4096 + i * 1024);
      gload16(Bt + (size_t)(n0 + r) * K + k0 + ss * 8,
              (char*)Bsm + wv * 4096 + i * 1024);
    }
    __syncthreads();
    bf16x8 av[2][4], bv[2][4];
#pragma unroll
    for (int kk = 0; kk < 2; ++kk)
#pragma unroll
      for (int i = 0; i < 4; ++i) {
        int ra = wm + i * 16 + (ln & 15);
        int sa = (kk * 4 + (ln >> 4)) ^ (ra & 7);
        av[kk][i] = *(const bf16x8*)((const char*)Asm + ra * 128 + sa * 16);
        int rb = wn + i * 16 + (ln & 15);
        int sb = (kk * 4 + (ln >> 4)) ^ (rb & 7);
        bv[kk][i] = *(const bf16x8*)((const char*)Bsm + rb * 128 + sb * 16);
      }
#pragma unroll
    for (int kk = 0; kk < 2; ++kk)
#pragma unroll
      for (int mi = 0; mi < 4; ++mi)
#pragma unroll
        for (int ni = 0; ni < 4; ++ni)
          acc[mi][ni] = __builtin_amdgcn_mfma_f32_16x16x32_bf16(
              av[kk][mi], bv[kk][ni], acc[mi][ni], 0, 0, 0);
    __syncthreads();
  }

  // C/D layout (m89-verified): col = lane&15, row = (lane>>4)*4 + j
#pragma unroll
  for (int mi = 0; mi < 4; ++mi)
#pragma unroll
    for (int ni = 0; ni < 4; ++ni)
#pragma unroll
      for (int j = 0; j < 4; ++j) {
        int row = m0 + wm + mi * 16 + (ln >> 4) * 4 + j;
        int col = n0 + wn + ni * 16 + (ln & 15);
        float v = acc[mi][ni][j];
        if constexpr (MODE == 0) {
          Cf[(size_t)row * N + col] = v;
        } else if constexpr (MODE == 1) {
          int part = col / 768;  // 128-col blocks never straddle parts
          int nn = col - part * 768;
          int h = nn >> 6, d = nn & 63;
          int b = row >> 10, s = row & 1023;
          size_t bh = (size_t)(b * Hn + h);
          float bias = (part == 0) ? bias0[nn] : (part == 1) ? bias1[nn] : bias2[nn];
          short o = f2bs(v + bias);
          if (part == 0)       Qo[(bh * Sn + s) * Dn + d] = o;
          else if (part == 1)  Ko[(bh * Sn + s) * Dn + d] = o;
          else                 Vto[(bh * Dn + d) * Sn + s] = o;  // pre-transposed V
        } else {
          float u = v + bias0[col];
          float gl = 0.5f * u * (1.0f + erff(u * 0.70710678118654752f));
          Cb[(size_t)row * N + col] = f2bs(gl);
        }
      }
}

// ---------------- flash attention with multiplicative Sierpinski mask ----------------
// Q,K: [BH][S][D] bf16   Vt: [BH][D][S] bf16   att: [B][S][E] bf16
__global__ __launch_bounds__(256, 2) void attn_kernel(
    const short* __restrict__ Qb, const short* __restrict__ Kb,
    const short* __restrict__ Vt, short* __restrict__ att) {
  __shared__ short P_lds[4][16 * 64];
  const int tid = threadIdx.x, wv = tid >> 6, ln = tid & 63;
  const int bh = blockIdx.y;
  const int q0 = blockIdx.x * 64 + wv * 16;
  const int b = bh / Hn, h = bh - b * Hn;

  const size_t qoff = ((size_t)bh * Sn + q0) * Dn;
  bf16x8 aq[2];
#pragma unroll
  for (int kk = 0; kk < 2; ++kk)
    aq[kk] = *(const bf16x8*)(Qb + qoff + (size_t)(ln & 15) * Dn + kk * 32 + (ln >> 4) * 8);

  f32x4 o_acc[4] = {};
  float m_run[4], l_run[4];
#pragma unroll
  for (int j = 0; j < 4; ++j) { m_run[j] = -1e30f; l_run[j] = 0.f; }

  short* Pw = (short*)&P_lds[wv][0];

  for (int kt = 0; kt < Sn / 64; ++kt) {
    f32x4 s_acc[4] = {};
#pragma unroll
    for (int ni = 0; ni < 4; ++ni)
#pragma unroll
      for (int kk = 0; kk < 2; ++kk) {
        const bf16x8 bk = *(const bf16x8*)(
            Kb + ((size_t)bh * Sn + kt * 64 + ni * 16 + (ln & 15)) * Dn + kk * 32 + (ln >> 4) * 8);
        s_acc[ni] = __builtin_amdgcn_mfma_f32_16x16x32_bf16(aq[kk], bk, s_acc[ni], 0, 0, 0);
      }
    // multiplicative mask BEFORE softmax: masked scores become 0 (not -inf)
    float vals[4][4];
#pragma unroll
    for (int ni = 0; ni < 4; ++ni)
#pragma unroll
      for (int j = 0; j < 4; ++j) {
        int q = q0 + (ln >> 4) * 4 + j;
        int k = kt * 64 + ni * 16 + (ln & 15);
        vals[ni][j] = ((q & k) == 0) ? s_acc[ni][j] * 0.125f : 0.f;
      }
#pragma unroll
    for (int j = 0; j < 4; ++j) {
      float pm = fmaxf(fmaxf(vals[0][j], vals[1][j]), fmaxf(vals[2][j], vals[3][j]));
#pragma unroll
      for (int o = 1; o < 16; o <<= 1) pm = fmaxf(pm, __shfl_xor(pm, o));
      float mn = fmaxf(m_run[j], pm);
      float sc = __expf(m_run[j] - mn);
      float ps = 0.f;
#pragma unroll
      for (int ni = 0; ni < 4; ++ni) {
        float p = __expf(vals[ni][j] - mn);
        ps += p;
        vals[ni][j] = p;
      }
#pragma unroll
      for (int o = 1; o < 16; o <<= 1) ps += __shfl_xor(ps, o);
      l_run[j] = l_run[j] * sc + ps;
      m_run[j] = mn;
#pragma unroll
      for (int di = 0; di < 4; ++di) o_acc[di][j] *= sc;
    }
    // P -> LDS (XOR-swizzled 16B slots), per-wave private region
#pragma unroll
    for (int ni = 0; ni < 4; ++ni)
#pragma unroll
      for (int j = 0; j < 4; ++j) {
        int prow = (ln >> 4) * 4 + j;
        int pcol = ni * 16 + (ln & 15);
        int sw = (pcol >> 3) ^ (prow & 7);
        Pw[prow * 64 + sw * 8 + (pcol & 7)] = f2bs(vals[ni][j]);
      }
    // PV
#pragma unroll
    for (int kk = 0; kk < 2; ++kk) {
      int prow = ln & 15;
      int sw = (kk * 4 + (ln >> 4)) ^ (prow & 7);
      bf16x8 ap = *(const bf16x8*)(Pw + prow * 64 + sw * 8);
#pragma unroll
      for (int di = 0; di < 4; ++di) {
        const bf16x8 bv = *(const bf16x8*)(
            Vt + ((size_t)bh * Dn + di * 16 + (ln & 15)) * Sn + kt * 64 + kk * 32 + (ln >> 4) * 8);
        o_acc[di] = __builtin_amdgcn_mfma_f32_16x16x32_bf16(ap, bv, o_acc[di], 0, 0, 0);
      }
    }
  }
#pragma unroll
  for (int di = 0; di < 4; ++di)
#pragma unroll
    for (int j = 0; j < 4; ++j) {
      int s = q0 + (ln >> 4) * 4 + j;
      int e = h * 64 + di * 16 + (ln & 15);
      att[((size_t)b * Sn + s) * En + e] = f2bs(o_acc[di][j] / l_run[j]);
    }
}

// ---------------- residual + bias + LayerNorm (two-pass, f32) ----------------
__device__ __forceinline__ float block_reduce_sum(float v, float* sbuf) {
#pragma unroll
  for (int o = 32; o > 0; o >>= 1) v += __shfl_down(v, o);
  int wv = threadIdx.x >> 6, ln = threadIdx.x & 63;
  __syncthreads();
  if (ln == 0) sbuf[wv] = v;
  __syncthreads();
  return sbuf[0] + sbuf[1] + sbuf[2] + sbuf[3];
}

__global__ __launch_bounds__(256) void ln_kernel(
    const float* __restrict__ xr, const float* __restrict__ yr,
    const float* __restrict__ bias, const float* __restrict__ g,
    const float* __restrict__ be, float* __restrict__ outf,
    short* __restrict__ outb) {
  __shared__ float sbuf[4];
  int row = blockIdx.x, tid = threadIdx.x;
  size_t base = (size_t)row * En;
  float u[3];
  float s = 0.f;
#pragma unroll
  for (int t = 0; t < 3; ++t) {
    int i = tid + t * 256;
    u[t] = xr[base + i] + yr[base + i] + bias[i];
    s += u[t];
  }
  s = block_reduce_sum(s, sbuf);
  float mean = s * (1.0f / En);
  float s2 = 0.f;
#pragma unroll
  for (int t = 0; t < 3; ++t) { float d = u[t] - mean; s2 += d * d; }
  s2 = block_reduce_sum(s2, sbuf);
  float rstd = rsqrtf(s2 * (1.0f / En) + 1e-5f);
#pragma unroll
  for (int t = 0; t < 3; ++t) {
    int i = tid + t * 256;
    float o = (u[t] - mean) * rstd * g[i] + be[i];
    outf[base + i] = o;
    if (outb) outb[base + i] = f2bs(o);
  }
}

// ---------------- launch ----------------
extern "C" void kernel_launch(void* const* d_in, const int* in_sizes, int n_in,
                              void* d_out, int out_size, void* d_ws, size_t ws_size,
                              hipStream_t stream) {
  const float* x   = (const float*)d_in[0];
  const float* Wq  = (const float*)d_in[2];
  const float* bq  = (const float*)d_in[3];
  const float* Wk  = (const float*)d_in[4];
  const float* bk  = (const float*)d_in[5];
  const float* Wv  = (const float*)d_in[6];
  const float* bv  = (const float*)d_in[7];
  const float* Wo  = (const float*)d_in[8];
  const float* bo  = (const float*)d_in[9];
  const float* W1  = (const float*)d_in[10];
  const float* b1  = (const float*)d_in[11];
  const float* W2  = (const float*)d_in[12];
  const float* b2  = (const float*)d_in[13];
  const float* g1  = (const float*)d_in[14];
  const float* be1 = (const float*)d_in[15];
  const float* g2  = (const float*)d_in[16];
  const float* be2 = (const float*)d_in[17];
  float* out = (float*)d_out;
  char* ws = (char*)d_ws;

  // ---- workspace layout (bytes), total 70,778,880 (~67.5 MB) ----
  // Transient pool [0, 29884416): phase1-3 buffers; ff1 overlays it in phase 5+
  constexpr size_t OFF_XB    = 0;          // 4096x768  bf16 (xb; attb alias after QKV)
  constexpr size_t OFF_WTQKV = 6291456;    // 2304x768  bf16 (dead after QKV GEMM)
  constexpr size_t OFF_WTO   = 9830400;    // 768x768   bf16 (dead after Wo GEMM)
  constexpr size_t OFF_Q     = 11010048;   // [48][1024][64] bf16 (dead after attn)
  constexpr size_t OFF_K     = 17301504;
  constexpr size_t OFF_VT    = 23592960;   // [48][64][1024] bf16 (dead after attn)
  constexpr size_t OFF_FF1   = 0;          // 4096x3072 bf16 (25165824) overlays pool
  // Long-lived:
  constexpr size_t OFF_WT1   = 29884416;   // 3072x768  bf16
  constexpr size_t OFF_WT2   = 34603008;   // 768x3072  bf16
  constexpr size_t OFF_Y     = 39321600;   // 4096x768  f32 (y1, then y2)
  constexpr size_t OFF_X1    = 51904512;   // 4096x768  f32
  constexpr size_t OFF_X1B   = 64487424;   // 4096x768  bf16

  short* xb     = (short*)(ws + OFF_XB);
  short* attb   = (short*)(ws + OFF_XB);   // alias: xb dead after QKV GEMM
  short* wt_qkv = (short*)(ws + OFF_WTQKV);
  short* wt_o   = (short*)(ws + OFF_WTO);
  short* wt_1   = (short*)(ws + OFF_WT1);
  short* wt_2   = (short*)(ws + OFF_WT2);
  short* qb     = (short*)(ws + OFF_Q);
  short* kb     = (short*)(ws + OFF_K);
  short* vt     = (short*)(ws + OFF_VT);
  float* y1     = (float*)(ws + OFF_Y);
  float* y2     = (float*)(ws + OFF_Y);    // alias: y1 dead after LN1
  float* x1     = (float*)(ws + OFF_X1);
  short* x1b    = (short*)(ws + OFF_X1B);
  short* ff1    = (short*)(ws + OFF_FF1);  // alias: overlays entire transient pool

  dim3 tb(32, 8);
  cvt_f32_bf16<<<3072, 256, 0, stream>>>(x, xb, Mn * En);
  transpose_w<<<dim3(24, 24), tb, 0, stream>>>(Wq, wt_qkv,              768, 768);
  transpose_w<<<dim3(24, 24), tb, 0, stream>>>(Wk, wt_qkv + 768 * 768,  768, 768);
  transpose_w<<<dim3(24, 24), tb, 0, stream>>>(Wv, wt_qkv + 1536 * 768, 768, 768);
  transpose_w<<<dim3(24, 24), tb, 0, stream>>>(Wo, wt_o, 768, 768);
  transpose_w<<<dim3(96, 24), tb, 0, stream>>>(W1, wt_1, 768, 3072);
  transpose_w<<<dim3(24, 96), tb, 0, stream>>>(W2, wt_2, 3072, 768);

  gemm_bt<1><<<dim3(18, 32), 256, 0, stream>>>(xb, wt_qkv, Mn, 2304, 768,
      nullptr, nullptr, bq, bk, bv, qb, kb, vt);
  attn_kernel<<<dim3(16, 48), 256, 0, stream>>>(qb, kb, vt, attb);
  gemm_bt<0><<<dim3(6, 32), 256, 0, stream>>>(attb, wt_o, Mn, 768, 768,
      y1, nullptr, nullptr, nullptr, nullptr, nullptr, nullptr, nullptr);
  ln_kernel<<<Mn, 256, 0, stream>>>(x, y1, bo, g1, be1, x1, x1b);
  gemm_bt<2><<<dim3(24, 32), 256, 0, stream>>>(x1b, wt_1, Mn, 3072, 768,
      nullptr, ff1, b1, nullptr, nullptr, nullptr, nullptr, nullptr);
  gemm_bt<0><<<dim3(6, 32), 256, 0, stream>>>(ff1, wt_2, Mn, 768, 3072,
      y2, nullptr, nullptr, nullptr, nullptr, nullptr, nullptr, nullptr);
  ln_kernel<<<Mn, 256, 0, stream>>>(x1, y2, b2, g2, be2, out, nullptr);
}

// Round 4
// 314.759 us; speedup vs baseline: 1.1899x; 1.1899x over previous
//
#include <hip/hip_runtime.h>
#include <hip/hip_bf16.h>

// ---------------- problem constants ----------------
constexpr int Bn = 4, Sn = 1024, En = 768, Hn = 12, Fn = 3072, Dn = 64;
constexpr int Mn = Bn * Sn;  // 4096 rows

typedef __attribute__((ext_vector_type(8))) short bf16x8;
typedef __attribute__((ext_vector_type(4))) float f32x4;

__device__ __forceinline__ short f2bs(float f) {
  unsigned u = __builtin_bit_cast(unsigned, f);
  unsigned r = (u + 0x7fffu + ((u >> 16) & 1u)) >> 16;  // RNE
  return (short)(r & 0xffffu);
}

__device__ __forceinline__ float bs2f(short s) {
  unsigned u = ((unsigned)(unsigned short)s) << 16;
  return __builtin_bit_cast(float, u);
}

__device__ __forceinline__ void gload16(const void* g, void* l) {
  __builtin_amdgcn_global_load_lds(
      (const __attribute__((address_space(1))) void*)g,
      (__attribute__((address_space(3))) void*)l, 16, 0, 0);
}

// ---------------- prep kernels ----------------
__global__ __launch_bounds__(256) void cvt_f32_bf16(
    const float* __restrict__ in, short* __restrict__ out, int n) {
  int i = (blockIdx.x * 256 + threadIdx.x) * 4;
  if (i >= n) return;
  float4 f = *(const float4*)(in + i);
  short4 o;
  o.x = f2bs(f.x); o.y = f2bs(f.y); o.z = f2bs(f.z); o.w = f2bs(f.w);
  *(short4*)(out + i) = o;
}

// W [K][N] f32 -> Wt [N][K] bf16
__global__ __launch_bounds__(256) void transpose_w(
    const float* __restrict__ W, short* __restrict__ Wt, int K, int N) {
  __shared__ float t[32][33];
  int bx = blockIdx.x * 32, by = blockIdx.y * 32;
  int tx = threadIdx.x, ty = threadIdx.y;
#pragma unroll
  for (int i = ty; i < 32; i += 8)
    t[i][tx] = W[(size_t)(by + i) * N + bx + tx];
  __syncthreads();
#pragma unroll
  for (int i = ty; i < 32; i += 8)
    Wt[(size_t)(bx + i) * K + by + tx] = f2bs(t[tx][i]);
}

// per-(bh, 64-tile) V column sums: Vtile[bh][kt][d] = sum_{s in tile kt} V[bh][s][d]
__global__ __launch_bounds__(256) void vtile_sum(
    const short* __restrict__ Vt, float* __restrict__ Vtile) {
  int bh = blockIdx.x;
  int d = threadIdx.x & 63, g = threadIdx.x >> 6;  // g = 0..3
#pragma unroll
  for (int i = 0; i < 4; ++i) {
    int kt = g * 4 + i;
    float s = 0.f;
    const short* p = Vt + ((size_t)bh * Dn + d) * Sn + kt * 64;
#pragma unroll
    for (int c = 0; c < 8; ++c) {
      bf16x8 v = *(const bf16x8*)(p + c * 8);
#pragma unroll
      for (int e = 0; e < 8; ++e) s += bs2f(v[e]);
    }
    Vtile[((size_t)bh * 16 + kt) * 64 + d] = s;
  }
}

// ---------------- GEMM: C[M,N] = A[M,K](bf16) * Bt[N,K]^T(bf16) ----------------
// MODE 0: Cf = raw f32           MODE 1: QKV scatter (+bias) -> Qo/Ko/Vto bf16
// MODE 2: Cb = bf16 gelu(acc + bias0)
template <int MODE>
__global__ __launch_bounds__(256, 2) void gemm_bt(
    const short* __restrict__ A, const short* __restrict__ Bt,
    int M, int N, int K,
    float* __restrict__ Cf, short* __restrict__ Cb,
    const float* __restrict__ bias0, const float* __restrict__ bias1,
    const float* __restrict__ bias2,
    short* __restrict__ Qo, short* __restrict__ Ko, short* __restrict__ Vto) {
  __shared__ short Asm[128 * 64];
  __shared__ short Bsm[128 * 64];
  const int tid = threadIdx.x, wv = tid >> 6, ln = tid & 63;
  const int m0 = blockIdx.y * 128, n0 = blockIdx.x * 128;
  const int wm = (wv >> 1) * 64, wn = (wv & 1) * 64;
  f32x4 acc[4][4] = {};

  for (int k0 = 0; k0 < K; k0 += 64) {
    // stage 2x 16KB tiles: pre-swizzled global source -> linear LDS dest
#pragma unroll
    for (int i = 0; i < 4; ++i) {
      int off = wv * 4096 + i * 1024 + ln * 16;  // byte offset in tile
      int r = off >> 7, sl = (off >> 4) & 7, ss = sl ^ (r & 7);
      gload16(A + (size_t)(m0 + r) * K + k0 + ss * 8,
              (char*)Asm + wv * 4096 + i * 1024);
      gload16(Bt + (size_t)(n0 + r) * K + k0 + ss * 8,
              (char*)Bsm + wv * 4096 + i * 1024);
    }
    __syncthreads();
    bf16x8 av[2][4], bv[2][4];
#pragma unroll
    for (int kk = 0; kk < 2; ++kk)
#pragma unroll
      for (int i = 0; i < 4; ++i) {
        int ra = wm + i * 16 + (ln & 15);
        int sa = (kk * 4 + (ln >> 4)) ^ (ra & 7);
        av[kk][i] = *(const bf16x8*)((const char*)Asm + ra * 128 + sa * 16);
        int rb = wn + i * 16 + (ln & 15);
        int sb = (kk * 4 + (ln >> 4)) ^ (rb & 7);
        bv[kk][i] = *(const bf16x8*)((const char*)Bsm + rb * 128 + sb * 16);
      }
#pragma unroll
    for (int kk = 0; kk < 2; ++kk)
#pragma unroll
      for (int mi = 0; mi < 4; ++mi)
#pragma unroll
        for (int ni = 0; ni < 4; ++ni)
          acc[mi][ni] = __builtin_amdgcn_mfma_f32_16x16x32_bf16(
              av[kk][mi], bv[kk][ni], acc[mi][ni], 0, 0, 0);
    __syncthreads();
  }

  // C/D layout (m89-verified): col = lane&15, row = (lane>>4)*4 + j
#pragma unroll
  for (int mi = 0; mi < 4; ++mi)
#pragma unroll
    for (int ni = 0; ni < 4; ++ni)
#pragma unroll
      for (int j = 0; j < 4; ++j) {
        int row = m0 + wm + mi * 16 + (ln >> 4) * 4 + j;
        int col = n0 + wn + ni * 16 + (ln & 15);
        float v = acc[mi][ni][j];
        if constexpr (MODE == 0) {
          Cf[(size_t)row * N + col] = v;
        } else if constexpr (MODE == 1) {
          int part = col / 768;  // 128-col blocks never straddle parts
          int nn = col - part * 768;
          int h = nn >> 6, d = nn & 63;
          int b = row >> 10, s = row & 1023;
          size_t bh = (size_t)(b * Hn + h);
          float bias = (part == 0) ? bias0[nn] : (part == 1) ? bias1[nn] : bias2[nn];
          short o = f2bs(v + bias);
          if (part == 0)       Qo[(bh * Sn + s) * Dn + d] = o;
          else if (part == 1)  Ko[(bh * Sn + s) * Dn + d] = o;
          else                 Vto[(bh * Dn + d) * Sn + s] = o;  // pre-transposed V
        } else {
          float u = v + bias0[col];
          float gl = 0.5f * u * (1.0f + erff(u * 0.70710678118654752f));
          Cb[(size_t)row * N + col] = f2bs(gl);
        }
      }
}

// ---------------- sparse flash attention, multiplicative Sierpinski mask ----------------
// Tile (qt,kt) fully masked unless qt&kt==0 -> only 81/256 tiles computed.
// Fixed softmax shift m=0 (scores bounded): p=exp(s'), purely additive, so
// skipped tiles contribute 64 to denom and Vtile-sums to numerator (epilogue).
// Q,K: [BH][S][D] bf16   Vt: [BH][D][S] bf16   Vtile: [BH][16][64] f32
__device__ const int qt_order[16] = {0, 1, 2, 4, 8, 3, 5, 6, 9, 10, 12, 7, 11, 13, 14, 15};

__global__ __launch_bounds__(256, 2) void attn_kernel(
    const short* __restrict__ Qb, const short* __restrict__ Kb,
    const short* __restrict__ Vt, const float* __restrict__ Vtile,
    short* __restrict__ att) {
  __shared__ short Ksm[2][64 * 64];
  __shared__ short Vsm[2][64 * 64];
  __shared__ short P_lds[4][16 * 64];
  const int tid = threadIdx.x, wv = tid >> 6, ln = tid & 63;
  const int bh = blockIdx.x;              // 48
  const int qt = qt_order[blockIdx.y];    // heavy (qt=0) blocks first
  const int q0 = qt * 64 + wv * 16;
  const int b = bh / Hn, h = bh - b * Hn;
  const int notqt = (~qt) & 15;
  const int nv = 1 << __popc(notqt);      // visited tiles

  // Q fragment (A-operand), 16 rows per wave
  const size_t qoff = ((size_t)bh * Sn + q0) * Dn;
  bf16x8 aq[2];
#pragma unroll
  for (int kk = 0; kk < 2; ++kk)
    aq[kk] = *(const bf16x8*)(Qb + qoff + (size_t)(ln & 15) * Dn + kk * 32 + (ln >> 4) * 8);

  f32x4 o_acc[4] = {};
  float l_run[4] = {0.f, 0.f, 0.f, 0.f};
  short* Pw = (short*)&P_lds[wv][0];

  // stage K-tile + V-tile (8KB each) into LDS buf; pre-swizzled source,
  // linear LDS dest, swizzled read (rule #21 involution)
  auto stage = [&](int bufi, int kt) {
#pragma unroll
    for (int i = 0; i < 2; ++i) {
      int off = i * 4096 + wv * 1024 + ln * 16;
      int r = off >> 7, sl = (off >> 4) & 7, ss = sl ^ (r & 7);
      gload16(Kb + ((size_t)bh * Sn + (size_t)kt * 64 + r) * Dn + ss * 8,
              (char*)Ksm[bufi] + i * 4096 + wv * 1024);
      gload16(Vt + ((size_t)bh * Dn + r) * Sn + (size_t)kt * 64 + ss * 8,
              (char*)Vsm[bufi] + i * 4096 + wv * 1024);
    }
  };

  stage(0, 0);  // kt=0 always visited (0 & qt == 0)
  __syncthreads();
  int buf = 0, kt = 0;
  while (true) {
    const int ktn = ((kt | qt) + 1) & notqt;  // next visited tile; 0 => done
    if (ktn) stage(buf ^ 1, ktn);

    // QK^T from LDS
    f32x4 s_acc[4] = {};
#pragma unroll
    for (int kk = 0; kk < 2; ++kk)
#pragma unroll
      for (int ni = 0; ni < 4; ++ni) {
        int rb = ni * 16 + (ln & 15);
        int sb = (kk * 4 + (ln >> 4)) ^ (rb & 7);
        bf16x8 bk = *(const bf16x8*)((const char*)Ksm[buf] + rb * 128 + sb * 16);
        s_acc[ni] = __builtin_amdgcn_mfma_f32_16x16x32_bf16(aq[kk], bk, s_acc[ni], 0, 0, 0);
      }

    // mask + exp (fixed m=0), deferred per-lane denom, P -> LDS
#pragma unroll
    for (int ni = 0; ni < 4; ++ni)
#pragma unroll
      for (int j = 0; j < 4; ++j) {
        int q = q0 + (ln >> 4) * 4 + j;
        int k = kt * 64 + ni * 16 + (ln & 15);
        float p = ((q & k) == 0) ? __expf(s_acc[ni][j] * 0.125f) : 1.0f;
        l_run[j] += p;
        int prow = (ln >> 4) * 4 + j;
        int pcol = ni * 16 + (ln & 15);
        int sw = (pcol >> 3) ^ (prow & 7);
        Pw[prow * 64 + sw * 8 + (pcol & 7)] = f2bs(p);
      }

    // PV from LDS
#pragma unroll
    for (int kk = 0; kk < 2; ++kk) {
      int prow = ln & 15;
      int swp = (kk * 4 + (ln >> 4)) ^ (prow & 7);
      bf16x8 ap = *(const bf16x8*)(Pw + prow * 64 + swp * 8);
#pragma unroll
      for (int di = 0; di < 4; ++di) {
        int rv = di * 16 + (ln & 15);
        int sv = (kk * 4 + (ln >> 4)) ^ (rv & 7);
        bf16x8 bv = *(const bf16x8*)((const char*)Vsm[buf] + rv * 128 + sv * 16);
        o_acc[di] = __builtin_amdgcn_mfma_f32_16x16x32_bf16(ap, bv, o_acc[di], 0, 0, 0);
      }
    }

    __syncthreads();  // drains vmcnt (next tile staged) + guards buf reuse
    buf ^= 1;
    if (!ktn) break;
    kt = ktn;
  }

  // epilogue: skipped-tile corrections
  float vc[4] = {0.f, 0.f, 0.f, 0.f};
  for (int t = 0; t < 16; ++t)
    if (qt & t) {
#pragma unroll
      for (int di = 0; di < 4; ++di)
        vc[di] += Vtile[((size_t)bh * 16 + t) * 64 + di * 16 + (ln & 15)];
    }
  const float skip_l = 64.0f * (float)(16 - nv);
  float ltot[4];
#pragma unroll
  for (int j = 0; j < 4; ++j) {
    float l = l_run[j];
#pragma unroll
    for (int o = 1; o < 16; o <<= 1) l += __shfl_xor(l, o);
    ltot[j] = l + skip_l;
  }
#pragma unroll
  for (int di = 0; di < 4; ++di)
#pragma unroll
    for (int j = 0; j < 4; ++j) {
      int s = q0 + (ln >> 4) * 4 + j;
      int e = h * 64 + di * 16 + (ln & 15);
      att[((size_t)b * Sn + s) * En + e] = f2bs((o_acc[di][j] + vc[di]) / ltot[j]);
    }
}

// ---------------- residual + bias + LayerNorm (two-pass, f32) ----------------
__device__ __forceinline__ float block_reduce_sum(float v, float* sbuf) {
#pragma unroll
  for (int o = 32; o > 0; o >>= 1) v += __shfl_down(v, o);
  int wv = threadIdx.x >> 6, ln = threadIdx.x & 63;
  __syncthreads();
  if (ln == 0) sbuf[wv] = v;
  __syncthreads();
  return sbuf[0] + sbuf[1] + sbuf[2] + sbuf[3];
}

__global__ __launch_bounds__(256) void ln_kernel(
    const float* __restrict__ xr, const float* __restrict__ yr,
    const float* __restrict__ bias, const float* __restrict__ g,
    const float* __restrict__ be, float* __restrict__ outf,
    short* __restrict__ outb) {
  __shared__ float sbuf[4];
  int row = blockIdx.x, tid = threadIdx.x;
  size_t base = (size_t)row * En;
  float u[3];
  float s = 0.f;
#pragma unroll
  for (int t = 0; t < 3; ++t) {
    int i = tid + t * 256;
    u[t] = xr[base + i] + yr[base + i] + bias[i];
    s += u[t];
  }
  s = block_reduce_sum(s, sbuf);
  float mean = s * (1.0f / En);
  float s2 = 0.f;
#pragma unroll
  for (int t = 0; t < 3; ++t) { float d = u[t] - mean; s2 += d * d; }
  s2 = block_reduce_sum(s2, sbuf);
  float rstd = rsqrtf(s2 * (1.0f / En) + 1e-5f);
#pragma unroll
  for (int t = 0; t < 3; ++t) {
    int i = tid + t * 256;
    float o = (u[t] - mean) * rstd * g[i] + be[i];
    outf[base + i] = o;
    if (outb) outb[base + i] = f2bs(o);
  }
}

// ---------------- launch ----------------
extern "C" void kernel_launch(void* const* d_in, const int* in_sizes, int n_in,
                              void* d_out, int out_size, void* d_ws, size_t ws_size,
                              hipStream_t stream) {
  const float* x   = (const float*)d_in[0];
  const float* Wq  = (const float*)d_in[2];
  const float* bq  = (const float*)d_in[3];
  const float* Wk  = (const float*)d_in[4];
  const float* bk  = (const float*)d_in[5];
  const float* Wv  = (const float*)d_in[6];
  const float* bv  = (const float*)d_in[7];
  const float* Wo  = (const float*)d_in[8];
  const float* bo  = (const float*)d_in[9];
  const float* W1  = (const float*)d_in[10];
  const float* b1  = (const float*)d_in[11];
  const float* W2  = (const float*)d_in[12];
  const float* b2  = (const float*)d_in[13];
  const float* g1  = (const float*)d_in[14];
  const float* be1 = (const float*)d_in[15];
  const float* g2  = (const float*)d_in[16];
  const float* be2 = (const float*)d_in[17];
  float* out = (float*)d_out;
  char* ws = (char*)d_ws;

  // ---- workspace layout (bytes), total 70,778,880 (~67.5 MB) ----
  constexpr size_t OFF_XB    = 0;          // 4096x768  bf16 (xb; attb alias after QKV)
  constexpr size_t OFF_WTQKV = 6291456;    // 2304x768  bf16 (dead after QKV GEMM)
  constexpr size_t OFF_VTILE = 6291456;    // [48][16][64] f32 overlays dead wt_qkv
  constexpr size_t OFF_WTO   = 9830400;    // 768x768   bf16 (dead after Wo GEMM)
  constexpr size_t OFF_Q     = 11010048;   // [48][1024][64] bf16 (dead after attn)
  constexpr size_t OFF_K     = 17301504;
  constexpr size_t OFF_VT    = 23592960;   // [48][64][1024] bf16 (dead after attn)
  constexpr size_t OFF_FF1   = 0;          // 4096x3072 bf16 overlays transient pool
  // Long-lived:
  constexpr size_t OFF_WT1   = 29884416;   // 3072x768  bf16
  constexpr size_t OFF_WT2   = 34603008;   // 768x3072  bf16
  constexpr size_t OFF_Y     = 39321600;   // 4096x768  f32 (y1, then y2)
  constexpr size_t OFF_X1    = 51904512;   // 4096x768  f32
  constexpr size_t OFF_X1B   = 64487424;   // 4096x768  bf16

  short* xb     = (short*)(ws + OFF_XB);
  short* attb   = (short*)(ws + OFF_XB);
  short* wt_qkv = (short*)(ws + OFF_WTQKV);
  float* vtile  = (float*)(ws + OFF_VTILE);
  short* wt_o   = (short*)(ws + OFF_WTO);
  short* wt_1   = (short*)(ws + OFF_WT1);
  short* wt_2   = (short*)(ws + OFF_WT2);
  short* qb     = (short*)(ws + OFF_Q);
  short* kb     = (short*)(ws + OFF_K);
  short* vt     = (short*)(ws + OFF_VT);
  float* y1     = (float*)(ws + OFF_Y);
  float* y2     = (float*)(ws + OFF_Y);
  float* x1     = (float*)(ws + OFF_X1);
  short* x1b    = (short*)(ws + OFF_X1B);
  short* ff1    = (short*)(ws + OFF_FF1);

  dim3 tb(32, 8);
  cvt_f32_bf16<<<3072, 256, 0, stream>>>(x, xb, Mn * En);
  transpose_w<<<dim3(24, 24), tb, 0, stream>>>(Wq, wt_qkv,              768, 768);
  transpose_w<<<dim3(24, 24), tb, 0, stream>>>(Wk, wt_qkv + 768 * 768,  768, 768);
  transpose_w<<<dim3(24, 24), tb, 0, stream>>>(Wv, wt_qkv + 1536 * 768, 768, 768);
  transpose_w<<<dim3(24, 24), tb, 0, stream>>>(Wo, wt_o, 768, 768);
  transpose_w<<<dim3(96, 24), tb, 0, stream>>>(W1, wt_1, 768, 3072);
  transpose_w<<<dim3(24, 96), tb, 0, stream>>>(W2, wt_2, 3072, 768);

  gemm_bt<1><<<dim3(18, 32), 256, 0, stream>>>(xb, wt_qkv, Mn, 2304, 768,
      nullptr, nullptr, bq, bk, bv, qb, kb, vt);
  vtile_sum<<<48, 256, 0, stream>>>(vt, vtile);
  attn_kernel<<<dim3(48, 16), 256, 0, stream>>>(qb, kb, vt, vtile, attb);
  gemm_bt<0><<<dim3(6, 32), 256, 0, stream>>>(attb, wt_o, Mn, 768, 768,
      y1, nullptr, nullptr, nullptr, nullptr, nullptr, nullptr, nullptr);
  ln_kernel<<<Mn, 256, 0, stream>>>(x, y1, bo, g1, be1, x1, x1b);
  gemm_bt<2><<<dim3(24, 32), 256, 0, stream>>>(x1b, wt_1, Mn, 3072, 768,
      nullptr, ff1, b1, nullptr, nullptr, nullptr, nullptr, nullptr);
  gemm_bt<0><<<dim3(6, 32), 256, 0, stream>>>(ff1, wt_2, Mn, 768, 3072,
      y2, nullptr, nullptr, nullptr, nullptr, nullptr, nullptr, nullptr);
  ln_kernel<<<Mn, 256, 0, stream>>>(x1, y2, b2, g2, be2, out, nullptr);
}

// Round 8
// 302.386 us; speedup vs baseline: 1.2386x; 1.0409x over previous
//
#include <hip/hip_runtime.h>
#include <hip/hip_bf16.h>

// ---------------- problem constants ----------------
constexpr int Bn = 4, Sn = 1024, En = 768, Hn = 12, Fn = 3072, Dn = 64;
constexpr int Mn = Bn * Sn;  // 4096 rows

typedef __attribute__((ext_vector_type(8))) short bf16x8;
typedef __attribute__((ext_vector_type(4))) float f32x4;

__device__ __forceinline__ short f2bs(float f) {
  unsigned u = __builtin_bit_cast(unsigned, f);
  unsigned r = (u + 0x7fffu + ((u >> 16) & 1u)) >> 16;  // RNE
  return (short)(r & 0xffffu);
}

__device__ __forceinline__ float bs2f(short s) {
  unsigned u = ((unsigned)(unsigned short)s) << 16;
  return __builtin_bit_cast(float, u);
}

__device__ __forceinline__ void gload16(const void* g, void* l) {
  __builtin_amdgcn_global_load_lds(
      (const __attribute__((address_space(1))) void*)g,
      (__attribute__((address_space(3))) void*)l, 16, 0, 0);
}

// ---------------- prep kernels ----------------
__global__ __launch_bounds__(256) void cvt_f32_bf16(
    const float* __restrict__ in, short* __restrict__ out, int n) {
  int i = (blockIdx.x * 256 + threadIdx.x) * 4;
  if (i >= n) return;
  float4 f = *(const float4*)(in + i);
  short4 o;
  o.x = f2bs(f.x); o.y = f2bs(f.y); o.z = f2bs(f.z); o.w = f2bs(f.w);
  *(short4*)(out + i) = o;
}

// W [K][N] f32 -> Wt [N][K] bf16
__global__ __launch_bounds__(256) void transpose_w(
    const float* __restrict__ W, short* __restrict__ Wt, int K, int N) {
  __shared__ float t[32][33];
  int bx = blockIdx.x * 32, by = blockIdx.y * 32;
  int tx = threadIdx.x, ty = threadIdx.y;
#pragma unroll
  for (int i = ty; i < 32; i += 8)
    t[i][tx] = W[(size_t)(by + i) * N + bx + tx];
  __syncthreads();
#pragma unroll
  for (int i = ty; i < 32; i += 8)
    Wt[(size_t)(bx + i) * K + by + tx] = f2bs(t[tx][i]);
}

// per-(bh, 64-tile) V column sums: Vtile[bh][kt][d] = sum_{s in tile kt} V[bh][s][d]
__global__ __launch_bounds__(256) void vtile_sum(
    const short* __restrict__ Vt, float* __restrict__ Vtile) {
  int bh = blockIdx.x;
  int d = threadIdx.x & 63, g = threadIdx.x >> 6;  // g = 0..3
#pragma unroll
  for (int i = 0; i < 4; ++i) {
    int kt = g * 4 + i;
    float s = 0.f;
    const short* p = Vt + ((size_t)bh * Dn + d) * Sn + kt * 64;
#pragma unroll
    for (int c = 0; c < 8; ++c) {
      bf16x8 v = *(const bf16x8*)(p + c * 8);
#pragma unroll
      for (int e = 0; e < 8; ++e) s += bs2f(v[e]);
    }
    Vtile[((size_t)bh * 16 + kt) * 64 + d] = s;
  }
}

// ---------------- GEMM: C[M,N] = A[M,K](bf16) * Bt[N,K]^T(bf16) ----------------
// Tiles: BM x BN, 2x2 waves, BK=64, double-buffered LDS (T3 2-phase minimum:
// stage next tile before compute, ONE barrier per K-step). XCD-chunked block
// swizzle (grid size always % 8 == 0 -> bijective).
// MODE 0: Cf = raw f32    MODE 1: QKV scatter (+bias) -> Qo/Ko/Vto bf16
// MODE 2: Cb = bf16 gelu(acc + bias0)
template <int BM, int BN, int MODE, int OCC>
__global__ __launch_bounds__(256, OCC) void gemm_bt(
    const short* __restrict__ A, const short* __restrict__ Bt,
    int M, int N, int K,
    float* __restrict__ Cf, short* __restrict__ Cb,
    const float* __restrict__ bias0, const float* __restrict__ bias1,
    const float* __restrict__ bias2,
    short* __restrict__ Qo, short* __restrict__ Ko, short* __restrict__ Vto) {
  constexpr int WM = BM / 2, WN = BN / 2;
  constexpr int MR = WM / 16, NR = WN / 16;
  __shared__ short Asm[2][BM * 64];
  __shared__ short Bsm[2][BN * 64];
  const int tid = threadIdx.x, wv = tid >> 6, ln = tid & 63;

  // XCD-chunked swizzle: hardware round-robins dispatch index over 8 XCDs;
  // remap so each XCD gets a CONTIGUOUS logical chunk (shared A-strips in L2).
  const int gx = gridDim.x;
  const int nwg = gx * gridDim.y;
  const int d = blockIdx.y * gx + blockIdx.x;
  const int l = (d & 7) * (nwg >> 3) + (d >> 3);
  const int m0 = (l / gx) * BM, n0 = (l % gx) * BN;

  const int wm = (wv >> 1) * WM, wn = (wv & 1) * WN;
  f32x4 acc[MR][NR] = {};

  // stage one K-step tile pair: pre-swizzled global source -> linear LDS dest
  auto stage = [&](int bi, int k0) {
#pragma unroll
    for (int p = 0; p < BM / 32; ++p) {
      int off = p * 4096 + wv * 1024 + ln * 16;  // byte offset in A tile
      int r = off >> 7, sl = (off >> 4) & 7, ss = sl ^ (r & 7);
      gload16(A + (size_t)(m0 + r) * K + k0 + ss * 8,
              (char*)Asm[bi] + p * 4096 + wv * 1024);
    }
#pragma unroll
    for (int p = 0; p < BN / 32; ++p) {
      int off = p * 4096 + wv * 1024 + ln * 16;
      int r = off >> 7, sl = (off >> 4) & 7, ss = sl ^ (r & 7);
      gload16(Bt + (size_t)(n0 + r) * K + k0 + ss * 8,
              (char*)Bsm[bi] + p * 4096 + wv * 1024);
    }
  };

  const int nt = K >> 6;
  stage(0, 0);
  int buf = 0;
  for (int t = 0; t < nt; ++t) {
    __syncthreads();  // drains tile-t staging (vmcnt) + guards buffer reuse
    if (t + 1 < nt) stage(buf ^ 1, (t + 1) * 64);
    bf16x8 av[2][MR], bv[2][NR];
#pragma unroll
    for (int kk = 0; kk < 2; ++kk) {
#pragma unroll
      for (int i = 0; i < MR; ++i) {
        int ra = wm + i * 16 + (ln & 15);
        int sa = (kk * 4 + (ln >> 4)) ^ (ra & 7);
        av[kk][i] = *(const bf16x8*)((const char*)Asm[buf] + ra * 128 + sa * 16);
      }
#pragma unroll
      for (int i = 0; i < NR; ++i) {
        int rb = wn + i * 16 + (ln & 15);
        int sb = (kk * 4 + (ln >> 4)) ^ (rb & 7);
        bv[kk][i] = *(const bf16x8*)((const char*)Bsm[buf] + rb * 128 + sb * 16);
      }
    }
#pragma unroll
    for (int kk = 0; kk < 2; ++kk)
#pragma unroll
      for (int mi = 0; mi < MR; ++mi)
#pragma unroll
        for (int ni = 0; ni < NR; ++ni)
          acc[mi][ni] = __builtin_amdgcn_mfma_f32_16x16x32_bf16(
              av[kk][mi], bv[kk][ni], acc[mi][ni], 0, 0, 0);
    buf ^= 1;
  }

  // C/D layout (m89-verified): col = lane&15, row = (lane>>4)*4 + j
#pragma unroll
  for (int mi = 0; mi < MR; ++mi)
#pragma unroll
    for (int ni = 0; ni < NR; ++ni)
#pragma unroll
      for (int j = 0; j < 4; ++j) {
        int row = m0 + wm + mi * 16 + (ln >> 4) * 4 + j;
        int col = n0 + wn + ni * 16 + (ln & 15);
        float v = acc[mi][ni][j];
        if constexpr (MODE == 0) {
          Cf[(size_t)row * N + col] = v;
        } else if constexpr (MODE == 1) {
          int part = col / 768;  // tile cols never straddle parts
          int nn = col - part * 768;
          int h = nn >> 6, dd = nn & 63;
          int b = row >> 10, s = row & 1023;
          size_t bh = (size_t)(b * Hn + h);
          float bias = (part == 0) ? bias0[nn] : (part == 1) ? bias1[nn] : bias2[nn];
          short o = f2bs(v + bias);
          if (part == 0)       Qo[(bh * Sn + s) * Dn + dd] = o;
          else if (part == 1)  Ko[(bh * Sn + s) * Dn + dd] = o;
          else                 Vto[(bh * Dn + dd) * Sn + s] = o;  // pre-transposed V
        } else {
          float u = v + bias0[col];
          float gl = 0.5f * u * (1.0f + erff(u * 0.70710678118654752f));
          Cb[(size_t)row * N + col] = f2bs(gl);
        }
      }
}

// ---------------- sparse flash attention, multiplicative Sierpinski mask ----------------
// Tile (qt,kt) fully masked unless qt&kt==0 -> only 81/256 tiles computed.
// Fixed softmax shift m=0 (scores bounded): p=exp(s'), purely additive, so
// skipped tiles contribute 64 to denom and Vtile-sums to numerator (epilogue).
// Q,K: [BH][S][D] bf16   Vt: [BH][D][S] bf16   Vtile: [BH][16][64] f32
__device__ const int qt_order[16] = {0, 1, 2, 4, 8, 3, 5, 6, 9, 10, 12, 7, 11, 13, 14, 15};

__global__ __launch_bounds__(256, 2) void attn_kernel(
    const short* __restrict__ Qb, const short* __restrict__ Kb,
    const short* __restrict__ Vt, const float* __restrict__ Vtile,
    short* __restrict__ att) {
  __shared__ short Ksm[2][64 * 64];
  __shared__ short Vsm[2][64 * 64];
  __shared__ short P_lds[4][16 * 64];
  const int tid = threadIdx.x, wv = tid >> 6, ln = tid & 63;
  const int bh = blockIdx.x;              // 48
  const int qt = qt_order[blockIdx.y];    // heavy (qt=0) blocks first
  const int q0 = qt * 64 + wv * 16;
  const int b = bh / Hn, h = bh - b * Hn;
  const int notqt = (~qt) & 15;
  const int nv = 1 << __popc(notqt);      // visited tiles

  // Q fragment (A-operand), 16 rows per wave
  const size_t qoff = ((size_t)bh * Sn + q0) * Dn;
  bf16x8 aq[2];
#pragma unroll
  for (int kk = 0; kk < 2; ++kk)
    aq[kk] = *(const bf16x8*)(Qb + qoff + (size_t)(ln & 15) * Dn + kk * 32 + (ln >> 4) * 8);

  f32x4 o_acc[4] = {};
  float l_run[4] = {0.f, 0.f, 0.f, 0.f};
  short* Pw = (short*)&P_lds[wv][0];

  // stage K-tile + V-tile (8KB each) into LDS buf; pre-swizzled source,
  // linear LDS dest, swizzled read (rule #21 involution)
  auto stage = [&](int bufi, int kt) {
#pragma unroll
    for (int i = 0; i < 2; ++i) {
      int off = i * 4096 + wv * 1024 + ln * 16;
      int r = off >> 7, sl = (off >> 4) & 7, ss = sl ^ (r & 7);
      gload16(Kb + ((size_t)bh * Sn + (size_t)kt * 64 + r) * Dn + ss * 8,
              (char*)Ksm[bufi] + i * 4096 + wv * 1024);
      gload16(Vt + ((size_t)bh * Dn + r) * Sn + (size_t)kt * 64 + ss * 8,
              (char*)Vsm[bufi] + i * 4096 + wv * 1024);
    }
  };

  stage(0, 0);  // kt=0 always visited (0 & qt == 0)
  __syncthreads();
  int buf = 0, kt = 0;
  while (true) {
    const int ktn = ((kt | qt) + 1) & notqt;  // next visited tile; 0 => done
    if (ktn) stage(buf ^ 1, ktn);

    // QK^T from LDS
    f32x4 s_acc[4] = {};
#pragma unroll
    for (int kk = 0; kk < 2; ++kk)
#pragma unroll
      for (int ni = 0; ni < 4; ++ni) {
        int rb = ni * 16 + (ln & 15);
        int sb = (kk * 4 + (ln >> 4)) ^ (rb & 7);
        bf16x8 bk = *(const bf16x8*)((const char*)Ksm[buf] + rb * 128 + sb * 16);
        s_acc[ni] = __builtin_amdgcn_mfma_f32_16x16x32_bf16(aq[kk], bk, s_acc[ni], 0, 0, 0);
      }

    // mask + exp (fixed m=0), deferred per-lane denom, P -> LDS
#pragma unroll
    for (int ni = 0; ni < 4; ++ni)
#pragma unroll
      for (int j = 0; j < 4; ++j) {
        int q = q0 + (ln >> 4) * 4 + j;
        int k = kt * 64 + ni * 16 + (ln & 15);
        float p = ((q & k) == 0) ? __expf(s_acc[ni][j] * 0.125f) : 1.0f;
        l_run[j] += p;
        int prow = (ln >> 4) * 4 + j;
        int pcol = ni * 16 + (ln & 15);
        int sw = (pcol >> 3) ^ (prow & 7);
        Pw[prow * 64 + sw * 8 + (pcol & 7)] = f2bs(p);
      }

    // PV from LDS
#pragma unroll
    for (int kk = 0; kk < 2; ++kk) {
      int prow = ln & 15;
      int swp = (kk * 4 + (ln >> 4)) ^ (prow & 7);
      bf16x8 ap = *(const bf16x8*)(Pw + prow * 64 + swp * 8);
#pragma unroll
      for (int di = 0; di < 4; ++di) {
        int rv = di * 16 + (ln & 15);
        int sv = (kk * 4 + (ln >> 4)) ^ (rv & 7);
        bf16x8 bv = *(const bf16x8*)((const char*)Vsm[buf] + rv * 128 + sv * 16);
        o_acc[di] = __builtin_amdgcn_mfma_f32_16x16x32_bf16(ap, bv, o_acc[di], 0, 0, 0);
      }
    }

    __syncthreads();  // drains vmcnt (next tile staged) + guards buf reuse
    buf ^= 1;
    if (!ktn) break;
    kt = ktn;
  }

  // epilogue: skipped-tile corrections
  float vc[4] = {0.f, 0.f, 0.f, 0.f};
  for (int t = 0; t < 16; ++t)
    if (qt & t) {
#pragma unroll
      for (int di = 0; di < 4; ++di)
        vc[di] += Vtile[((size_t)bh * 16 + t) * 64 + di * 16 + (ln & 15)];
    }
  const float skip_l = 64.0f * (float)(16 - nv);
  float ltot[4];
#pragma unroll
  for (int j = 0; j < 4; ++j) {
    float l = l_run[j];
#pragma unroll
    for (int o = 1; o < 16; o <<= 1) l += __shfl_xor(l, o);
    ltot[j] = l + skip_l;
  }
#pragma unroll
  for (int di = 0; di < 4; ++di)
#pragma unroll
    for (int j = 0; j < 4; ++j) {
      int s = q0 + (ln >> 4) * 4 + j;
      int e = h * 64 + di * 16 + (ln & 15);
      att[((size_t)b * Sn + s) * En + e] = f2bs((o_acc[di][j] + vc[di]) / ltot[j]);
    }
}

// ---------------- residual + bias + LayerNorm (two-pass, f32) ----------------
__device__ __forceinline__ float block_reduce_sum(float v, float* sbuf) {
#pragma unroll
  for (int o = 32; o > 0; o >>= 1) v += __shfl_down(v, o);
  int wv = threadIdx.x >> 6, ln = threadIdx.x & 63;
  __syncthreads();
  if (ln == 0) sbuf[wv] = v;
  __syncthreads();
  return sbuf[0] + sbuf[1] + sbuf[2] + sbuf[3];
}

__global__ __launch_bounds__(256) void ln_kernel(
    const float* __restrict__ xr, const float* __restrict__ yr,
    const float* __restrict__ bias, const float* __restrict__ g,
    const float* __restrict__ be, float* __restrict__ outf,
    short* __restrict__ outb) {
  __shared__ float sbuf[4];
  int row = blockIdx.x, tid = threadIdx.x;
  size_t base = (size_t)row * En;
  float u[3];
  float s = 0.f;
#pragma unroll
  for (int t = 0; t < 3; ++t) {
    int i = tid + t * 256;
    u[t] = xr[base + i] + yr[base + i] + bias[i];
    s += u[t];
  }
  s = block_reduce_sum(s, sbuf);
  float mean = s * (1.0f / En);
  float s2 = 0.f;
#pragma unroll
  for (int t = 0; t < 3; ++t) { float d = u[t] - mean; s2 += d * d; }
  s2 = block_reduce_sum(s2, sbuf);
  float rstd = rsqrtf(s2 * (1.0f / En) + 1e-5f);
#pragma unroll
  for (int t = 0; t < 3; ++t) {
    int i = tid + t * 256;
    float o = (u[t] - mean) * rstd * g[i] + be[i];
    outf[base + i] = o;
    if (outb) outb[base + i] = f2bs(o);
  }
}

// ---------------- launch ----------------
extern "C" void kernel_launch(void* const* d_in, const int* in_sizes, int n_in,
                              void* d_out, int out_size, void* d_ws, size_t ws_size,
                              hipStream_t stream) {
  const float* x   = (const float*)d_in[0];
  const float* Wq  = (const float*)d_in[2];
  const float* bq  = (const float*)d_in[3];
  const float* Wk  = (const float*)d_in[4];
  const float* bk  = (const float*)d_in[5];
  const float* Wv  = (const float*)d_in[6];
  const float* bv  = (const float*)d_in[7];
  const float* Wo  = (const float*)d_in[8];
  const float* bo  = (const float*)d_in[9];
  const float* W1  = (const float*)d_in[10];
  const float* b1  = (const float*)d_in[11];
  const float* W2  = (const float*)d_in[12];
  const float* b2  = (const float*)d_in[13];
  const float* g1  = (const float*)d_in[14];
  const float* be1 = (const float*)d_in[15];
  const float* g2  = (const float*)d_in[16];
  const float* be2 = (const float*)d_in[17];
  float* out = (float*)d_out;
  char* ws = (char*)d_ws;

  // ---- workspace layout (bytes), total 70,778,880 (~67.5 MB) ----
  constexpr size_t OFF_XB    = 0;          // 4096x768  bf16 (xb; attb alias after QKV)
  constexpr size_t OFF_WTQKV = 6291456;    // 2304x768  bf16 (dead after QKV GEMM)
  constexpr size_t OFF_VTILE = 6291456;    // [48][16][64] f32 overlays dead wt_qkv
  constexpr size_t OFF_WTO   = 9830400;    // 768x768   bf16 (dead after Wo GEMM)
  constexpr size_t OFF_Q     = 11010048;   // [48][1024][64] bf16 (dead after attn)
  constexpr size_t OFF_K     = 17301504;
  constexpr size_t OFF_VT    = 23592960;   // [48][64][1024] bf16 (dead after attn)
  constexpr size_t OFF_FF1   = 0;          // 4096x3072 bf16 overlays transient pool
  // Long-lived:
  constexpr size_t OFF_WT1   = 29884416;   // 3072x768  bf16
  constexpr size_t OFF_WT2   = 34603008;   // 768x3072  bf16
  constexpr size_t OFF_Y     = 39321600;   // 4096x768  f32 (y1, then y2)
  constexpr size_t OFF_X1    = 51904512;   // 4096x768  f32
  constexpr size_t OFF_X1B   = 64487424;   // 4096x768  bf16

  short* xb     = (short*)(ws + OFF_XB);
  short* attb   = (short*)(ws + OFF_XB);
  short* wt_qkv = (short*)(ws + OFF_WTQKV);
  float* vtile  = (float*)(ws + OFF_VTILE);
  short* wt_o   = (short*)(ws + OFF_WTO);
  short* wt_1   = (short*)(ws + OFF_WT1);
  short* wt_2   = (short*)(ws + OFF_WT2);
  short* qb     = (short*)(ws + OFF_Q);
  short* kb     = (short*)(ws + OFF_K);
  short* vt     = (short*)(ws + OFF_VT);
  float* y1     = (float*)(ws + OFF_Y);
  float* y2     = (float*)(ws + OFF_Y);
  float* x1     = (float*)(ws + OFF_X1);
  short* x1b    = (short*)(ws + OFF_X1B);
  short* ff1    = (short*)(ws + OFF_FF1);

  dim3 tb(32, 8);
  cvt_f32_bf16<<<3072, 256, 0, stream>>>(x, xb, Mn * En);
  transpose_w<<<dim3(24, 24), tb, 0, stream>>>(Wq, wt_qkv,              768, 768);
  transpose_w<<<dim3(24, 24), tb, 0, stream>>>(Wk, wt_qkv + 768 * 768,  768, 768);
  transpose_w<<<dim3(24, 24), tb, 0, stream>>>(Wv, wt_qkv + 1536 * 768, 768, 768);
  transpose_w<<<dim3(24, 24), tb, 0, stream>>>(Wo, wt_o, 768, 768);
  transpose_w<<<dim3(96, 24), tb, 0, stream>>>(W1, wt_1, 768, 3072);
  transpose_w<<<dim3(24, 96), tb, 0, stream>>>(W2, wt_2, 3072, 768);

  // QKV: 128x128 tiles, grid 18x32=576 (2.25 blk/CU)
  gemm_bt<128, 128, 1, 2><<<dim3(18, 32), 256, 0, stream>>>(xb, wt_qkv, Mn, 2304, 768,
      nullptr, nullptr, bq, bk, bv, qb, kb, vt);
  vtile_sum<<<48, 256, 0, stream>>>(vt, vtile);
  attn_kernel<<<dim3(48, 16), 256, 0, stream>>>(qb, kb, vt, vtile, attb);
  // Wo: N=768 -> 64x64 tiles, grid 12x64=768 (3 blk/CU)
  gemm_bt<64, 64, 0, 4><<<dim3(12, 64), 256, 0, stream>>>(attb, wt_o, Mn, 768, 768,
      y1, nullptr, nullptr, nullptr, nullptr, nullptr, nullptr, nullptr);
  ln_kernel<<<Mn, 256, 0, stream>>>(x, y1, bo, g1, be1, x1, x1b);
  // FF1: 128x128 tiles, grid 24x32=768 (3 blk/CU)
  gemm_bt<128, 128, 2, 2><<<dim3(24, 32), 256, 0, stream>>>(x1b, wt_1, Mn, 3072, 768,
      nullptr, ff1, b1, nullptr, nullptr, nullptr, nullptr, nullptr);
  // FF2: N=768 -> 64x64 tiles, grid 12x64=768 (3 blk/CU)
  gemm_bt<64, 64, 0, 4><<<dim3(12, 64), 256, 0, stream>>>(ff1, wt_2, Mn, 768, 3072,
      y2, nullptr, nullptr, nullptr, nullptr, nullptr, nullptr, nullptr);
  ln_kernel<<<Mn, 256, 0, stream>>>(x1, y2, b2, g2, be2, out, nullptr);
}

// Round 9
// 289.474 us; speedup vs baseline: 1.2938x; 1.0446x over previous
//
#include <hip/hip_runtime.h>
#include <hip/hip_bf16.h>

// ---------------- problem constants ----------------
constexpr int Bn = 4, Sn = 1024, En = 768, Hn = 12, Fn = 3072, Dn = 64;
constexpr int Mn = Bn * Sn;  // 4096 rows

typedef __attribute__((ext_vector_type(8))) short bf16x8;
typedef __attribute__((ext_vector_type(4))) float f32x4;

__device__ __forceinline__ short f2bs(float f) {
  unsigned u = __builtin_bit_cast(unsigned, f);
  unsigned r = (u + 0x7fffu + ((u >> 16) & 1u)) >> 16;  // RNE
  return (short)(r & 0xffffu);
}

__device__ __forceinline__ float bs2f(short s) {
  unsigned u = ((unsigned)(unsigned short)s) << 16;
  return __builtin_bit_cast(float, u);
}

__device__ __forceinline__ void gload16(const void* g, void* l) {
  __builtin_amdgcn_global_load_lds(
      (const __attribute__((address_space(1))) void*)g,
      (__attribute__((address_space(3))) void*)l, 16, 0, 0);
}

// ---------------- prep kernels ----------------
__global__ __launch_bounds__(256) void cvt_f32_bf16(
    const float* __restrict__ in, short* __restrict__ out, int n) {
  int i = (blockIdx.x * 256 + threadIdx.x) * 4;
  if (i >= n) return;
  float4 f = *(const float4*)(in + i);
  short4 o;
  o.x = f2bs(f.x); o.y = f2bs(f.y); o.z = f2bs(f.z); o.w = f2bs(f.w);
  *(short4*)(out + i) = o;
}

// W [K][N] f32 -> Wt [N][K] bf16
__global__ __launch_bounds__(256) void transpose_w(
    const float* __restrict__ W, short* __restrict__ Wt, int K, int N) {
  __shared__ float t[32][33];
  int bx = blockIdx.x * 32, by = blockIdx.y * 32;
  int tx = threadIdx.x, ty = threadIdx.y;
#pragma unroll
  for (int i = ty; i < 32; i += 8)
    t[i][tx] = W[(size_t)(by + i) * N + bx + tx];
  __syncthreads();
#pragma unroll
  for (int i = ty; i < 32; i += 8)
    Wt[(size_t)(bx + i) * K + by + tx] = f2bs(t[tx][i]);
}

// per-(bh, 64-tile) V column sums: Vtile[bh][kt][d] = sum_{s in tile kt} V[bh][s][d]
__global__ __launch_bounds__(256) void vtile_sum(
    const short* __restrict__ Vt, float* __restrict__ Vtile) {
  int bh = blockIdx.x;
  int d = threadIdx.x & 63, g = threadIdx.x >> 6;  // g = 0..3
#pragma unroll
  for (int i = 0; i < 4; ++i) {
    int kt = g * 4 + i;
    float s = 0.f;
    const short* p = Vt + ((size_t)bh * Dn + d) * Sn + kt * 64;
#pragma unroll
    for (int c = 0; c < 8; ++c) {
      bf16x8 v = *(const bf16x8*)(p + c * 8);
#pragma unroll
      for (int e = 0; e < 8; ++e) s += bs2f(v[e]);
    }
    Vtile[((size_t)bh * 16 + kt) * 64 + d] = s;
  }
}

// ---------------- GEMM: C[M,N] = A[M,K](bf16) * Bt[N,K]^T(bf16) ----------------
// Tiles: BM x BN, 2x2 waves, BK=64. DBUF=0: m97 single-buffer 2-barrier loop
// (32KB LDS -> 3+ blocks/CU; implicit wave-level overlap does latency hiding,
// per m114/m132 evidence). DBUF=1: 1-barrier double-buffer (only where the
// extra LDS doesn't cut residency, i.e. 64^2 tiles). XCD-chunked swizzle.
// MODE 0: Cf = raw f32    MODE 1: QKV scatter (+bias) -> Qo/Ko/Vto bf16
// MODE 2: Cb = bf16 gelu(acc + bias0)
template <int BM, int BN, int MODE, int OCC, int DBUF>
__global__ __launch_bounds__(256, OCC) void gemm_bt(
    const short* __restrict__ A, const short* __restrict__ Bt,
    int M, int N, int K,
    float* __restrict__ Cf, short* __restrict__ Cb,
    const float* __restrict__ bias0, const float* __restrict__ bias1,
    const float* __restrict__ bias2,
    short* __restrict__ Qo, short* __restrict__ Ko, short* __restrict__ Vto) {
  constexpr int WM = BM / 2, WN = BN / 2;
  constexpr int MR = WM / 16, NR = WN / 16;
  constexpr int NB = DBUF + 1;
  __shared__ short Asm[NB][BM * 64];
  __shared__ short Bsm[NB][BN * 64];
  const int tid = threadIdx.x, wv = tid >> 6, ln = tid & 63;

  // XCD-chunked swizzle: hardware round-robins dispatch index over 8 XCDs;
  // remap so each XCD gets a CONTIGUOUS logical chunk (shared A-strips in L2).
  const int gx = gridDim.x;
  const int nwg = gx * gridDim.y;
  const int d = blockIdx.y * gx + blockIdx.x;
  const int l = (d & 7) * (nwg >> 3) + (d >> 3);
  const int m0 = (l / gx) * BM, n0 = (l % gx) * BN;

  const int wm = (wv >> 1) * WM, wn = (wv & 1) * WN;
  f32x4 acc[MR][NR] = {};

  // stage one K-step tile pair: pre-swizzled global source -> linear LDS dest
  auto stage = [&](int bi, int k0) {
#pragma unroll
    for (int p = 0; p < BM / 32; ++p) {
      int off = p * 4096 + wv * 1024 + ln * 16;  // byte offset in A tile
      int r = off >> 7, sl = (off >> 4) & 7, ss = sl ^ (r & 7);
      gload16(A + (size_t)(m0 + r) * K + k0 + ss * 8,
              (char*)Asm[bi] + p * 4096 + wv * 1024);
    }
#pragma unroll
    for (int p = 0; p < BN / 32; ++p) {
      int off = p * 4096 + wv * 1024 + ln * 16;
      int r = off >> 7, sl = (off >> 4) & 7, ss = sl ^ (r & 7);
      gload16(Bt + (size_t)(n0 + r) * K + k0 + ss * 8,
              (char*)Bsm[bi] + p * 4096 + wv * 1024);
    }
  };

  auto compute = [&](int bi) {
    bf16x8 av[2][MR], bv[2][NR];
#pragma unroll
    for (int kk = 0; kk < 2; ++kk) {
#pragma unroll
      for (int i = 0; i < MR; ++i) {
        int ra = wm + i * 16 + (ln & 15);
        int sa = (kk * 4 + (ln >> 4)) ^ (ra & 7);
        av[kk][i] = *(const bf16x8*)((const char*)Asm[bi] + ra * 128 + sa * 16);
      }
#pragma unroll
      for (int i = 0; i < NR; ++i) {
        int rb = wn + i * 16 + (ln & 15);
        int sb = (kk * 4 + (ln >> 4)) ^ (rb & 7);
        bv[kk][i] = *(const bf16x8*)((const char*)Bsm[bi] + rb * 128 + sb * 16);
      }
    }
#pragma unroll
    for (int kk = 0; kk < 2; ++kk)
#pragma unroll
      for (int mi = 0; mi < MR; ++mi)
#pragma unroll
        for (int ni = 0; ni < NR; ++ni)
          acc[mi][ni] = __builtin_amdgcn_mfma_f32_16x16x32_bf16(
              av[kk][mi], bv[kk][ni], acc[mi][ni], 0, 0, 0);
  };

  const int nt = K >> 6;
  if constexpr (DBUF) {
    stage(0, 0);
    int buf = 0;
    for (int t = 0; t < nt; ++t) {
      __syncthreads();  // drains tile-t staging + guards buffer reuse
      if (t + 1 < nt) stage(buf ^ 1, (t + 1) * 64);
      compute(buf);
      buf ^= 1;
    }
  } else {
    for (int t = 0; t < nt; ++t) {
      stage(0, t * 64);
      __syncthreads();  // staging complete
      compute(0);
      __syncthreads();  // reads done before next-tile overwrite
    }
  }

  // C/D layout (m89-verified): col = lane&15, row = (lane>>4)*4 + j
#pragma unroll
  for (int mi = 0; mi < MR; ++mi)
#pragma unroll
    for (int ni = 0; ni < NR; ++ni)
#pragma unroll
      for (int j = 0; j < 4; ++j) {
        int row = m0 + wm + mi * 16 + (ln >> 4) * 4 + j;
        int col = n0 + wn + ni * 16 + (ln & 15);
        float v = acc[mi][ni][j];
        if constexpr (MODE == 0) {
          Cf[(size_t)row * N + col] = v;
        } else if constexpr (MODE == 1) {
          int part = col / 768;  // tile cols never straddle parts
          int nn = col - part * 768;
          int h = nn >> 6, dd = nn & 63;
          int b = row >> 10, s = row & 1023;
          size_t bh = (size_t)(b * Hn + h);
          float bias = (part == 0) ? bias0[nn] : (part == 1) ? bias1[nn] : bias2[nn];
          short o = f2bs(v + bias);
          if (part == 0)       Qo[(bh * Sn + s) * Dn + dd] = o;
          else if (part == 1)  Ko[(bh * Sn + s) * Dn + dd] = o;
          else                 Vto[(bh * Dn + dd) * Sn + s] = o;  // pre-transposed V
        } else {
          float u = v + bias0[col];
          float gl = 0.5f * u * (1.0f + erff(u * 0.70710678118654752f));
          Cb[(size_t)row * N + col] = f2bs(gl);
        }
      }
}

// ---------------- sparse flash attention, multiplicative Sierpinski mask ----------------
// Tile (qt,kt) fully masked unless qt&kt==0 -> only 81/256 tiles computed.
// Fixed softmax shift m=0 (scores bounded): p=exp(s'), purely additive, so
// skipped tiles contribute 64 to denom and Vtile-sums to numerator (epilogue).
// Q,K: [BH][S][D] bf16   Vt: [BH][D][S] bf16   Vtile: [BH][16][64] f32
__device__ const int qt_order[16] = {0, 1, 2, 4, 8, 3, 5, 6, 9, 10, 12, 7, 11, 13, 14, 15};

__global__ __launch_bounds__(256, 2) void attn_kernel(
    const short* __restrict__ Qb, const short* __restrict__ Kb,
    const short* __restrict__ Vt, const float* __restrict__ Vtile,
    short* __restrict__ att) {
  __shared__ short Ksm[2][64 * 64];
  __shared__ short Vsm[2][64 * 64];
  __shared__ short P_lds[4][16 * 64];
  const int tid = threadIdx.x, wv = tid >> 6, ln = tid & 63;
  const int bh = blockIdx.x;              // 48
  const int qt = qt_order[blockIdx.y];    // heavy (qt=0) blocks first
  const int q0 = qt * 64 + wv * 16;
  const int b = bh / Hn, h = bh - b * Hn;
  const int notqt = (~qt) & 15;
  const int nv = 1 << __popc(notqt);      // visited tiles

  // Q fragment (A-operand), 16 rows per wave
  const size_t qoff = ((size_t)bh * Sn + q0) * Dn;
  bf16x8 aq[2];
#pragma unroll
  for (int kk = 0; kk < 2; ++kk)
    aq[kk] = *(const bf16x8*)(Qb + qoff + (size_t)(ln & 15) * Dn + kk * 32 + (ln >> 4) * 8);

  f32x4 o_acc[4] = {};
  float l_run[4] = {0.f, 0.f, 0.f, 0.f};
  short* Pw = (short*)&P_lds[wv][0];

  // stage K-tile + V-tile (8KB each) into LDS buf; pre-swizzled source,
  // linear LDS dest, swizzled read (rule #21 involution)
  auto stage = [&](int bufi, int kt) {
#pragma unroll
    for (int i = 0; i < 2; ++i) {
      int off = i * 4096 + wv * 1024 + ln * 16;
      int r = off >> 7, sl = (off >> 4) & 7, ss = sl ^ (r & 7);
      gload16(Kb + ((size_t)bh * Sn + (size_t)kt * 64 + r) * Dn + ss * 8,
              (char*)Ksm[bufi] + i * 4096 + wv * 1024);
      gload16(Vt + ((size_t)bh * Dn + r) * Sn + (size_t)kt * 64 + ss * 8,
              (char*)Vsm[bufi] + i * 4096 + wv * 1024);
    }
  };

  stage(0, 0);  // kt=0 always visited (0 & qt == 0)
  __syncthreads();
  int buf = 0, kt = 0;
  while (true) {
    const int ktn = ((kt | qt) + 1) & notqt;  // next visited tile; 0 => done
    if (ktn) stage(buf ^ 1, ktn);

    // QK^T from LDS
    f32x4 s_acc[4] = {};
#pragma unroll
    for (int kk = 0; kk < 2; ++kk)
#pragma unroll
      for (int ni = 0; ni < 4; ++ni) {
        int rb = ni * 16 + (ln & 15);
        int sb = (kk * 4 + (ln >> 4)) ^ (rb & 7);
        bf16x8 bk = *(const bf16x8*)((const char*)Ksm[buf] + rb * 128 + sb * 16);
        s_acc[ni] = __builtin_amdgcn_mfma_f32_16x16x32_bf16(aq[kk], bk, s_acc[ni], 0, 0, 0);
      }

    // mask + exp (fixed m=0), deferred per-lane denom, P -> LDS
#pragma unroll
    for (int ni = 0; ni < 4; ++ni)
#pragma unroll
      for (int j = 0; j < 4; ++j) {
        int q = q0 + (ln >> 4) * 4 + j;
        int k = kt * 64 + ni * 16 + (ln & 15);
        float p = ((q & k) == 0) ? __expf(s_acc[ni][j] * 0.125f) : 1.0f;
        l_run[j] += p;
        int prow = (ln >> 4) * 4 + j;
        int pcol = ni * 16 + (ln & 15);
        int sw = (pcol >> 3) ^ (prow & 7);
        Pw[prow * 64 + sw * 8 + (pcol & 7)] = f2bs(p);
      }

    // PV from LDS
#pragma unroll
    for (int kk = 0; kk < 2; ++kk) {
      int prow = ln & 15;
      int swp = (kk * 4 + (ln >> 4)) ^ (prow & 7);
      bf16x8 ap = *(const bf16x8*)(Pw + prow * 64 + swp * 8);
#pragma unroll
      for (int di = 0; di < 4; ++di) {
        int rv = di * 16 + (ln & 15);
        int sv = (kk * 4 + (ln >> 4)) ^ (rv & 7);
        bf16x8 bv = *(const bf16x8*)((const char*)Vsm[buf] + rv * 128 + sv * 16);
        o_acc[di] = __builtin_amdgcn_mfma_f32_16x16x32_bf16(ap, bv, o_acc[di], 0, 0, 0);
      }
    }

    __syncthreads();  // drains vmcnt (next tile staged) + guards buf reuse
    buf ^= 1;
    if (!ktn) break;
    kt = ktn;
  }

  // epilogue: skipped-tile corrections
  float vc[4] = {0.f, 0.f, 0.f, 0.f};
  for (int t = 0; t < 16; ++t)
    if (qt & t) {
#pragma unroll
      for (int di = 0; di < 4; ++di)
        vc[di] += Vtile[((size_t)bh * 16 + t) * 64 + di * 16 + (ln & 15)];
    }
  const float skip_l = 64.0f * (float)(16 - nv);
  float ltot[4];
#pragma unroll
  for (int j = 0; j < 4; ++j) {
    float l = l_run[j];
#pragma unroll
    for (int o = 1; o < 16; o <<= 1) l += __shfl_xor(l, o);
    ltot[j] = l + skip_l;
  }
#pragma unroll
  for (int di = 0; di < 4; ++di)
#pragma unroll
    for (int j = 0; j < 4; ++j) {
      int s = q0 + (ln >> 4) * 4 + j;
      int e = h * 64 + di * 16 + (ln & 15);
      att[((size_t)b * Sn + s) * En + e] = f2bs((o_acc[di][j] + vc[di]) / ltot[j]);
    }
}

// ---------------- residual + bias + LayerNorm (two-pass, f32) ----------------
__device__ __forceinline__ float block_reduce_sum(float v, float* sbuf) {
#pragma unroll
  for (int o = 32; o > 0; o >>= 1) v += __shfl_down(v, o);
  int wv = threadIdx.x >> 6, ln = threadIdx.x & 63;
  __syncthreads();
  if (ln == 0) sbuf[wv] = v;
  __syncthreads();
  return sbuf[0] + sbuf[1] + sbuf[2] + sbuf[3];
}

__global__ __launch_bounds__(256) void ln_kernel(
    const float* __restrict__ xr, const float* __restrict__ yr,
    const float* __restrict__ bias, const float* __restrict__ g,
    const float* __restrict__ be, float* __restrict__ outf,
    short* __restrict__ outb) {
  __shared__ float sbuf[4];
  int row = blockIdx.x, tid = threadIdx.x;
  size_t base = (size_t)row * En;
  float u[3];
  float s = 0.f;
#pragma unroll
  for (int t = 0; t < 3; ++t) {
    int i = tid + t * 256;
    u[t] = xr[base + i] + yr[base + i] + bias[i];
    s += u[t];
  }
  s = block_reduce_sum(s, sbuf);
  float mean = s * (1.0f / En);
  float s2 = 0.f;
#pragma unroll
  for (int t = 0; t < 3; ++t) { float d = u[t] - mean; s2 += d * d; }
  s2 = block_reduce_sum(s2, sbuf);
  float rstd = rsqrtf(s2 * (1.0f / En) + 1e-5f);
#pragma unroll
  for (int t = 0; t < 3; ++t) {
    int i = tid + t * 256;
    float o = (u[t] - mean) * rstd * g[i] + be[i];
    outf[base + i] = o;
    if (outb) outb[base + i] = f2bs(o);
  }
}

// ---------------- launch ----------------
extern "C" void kernel_launch(void* const* d_in, const int* in_sizes, int n_in,
                              void* d_out, int out_size, void* d_ws, size_t ws_size,
                              hipStream_t stream) {
  const float* x   = (const float*)d_in[0];
  const float* Wq  = (const float*)d_in[2];
  const float* bq  = (const float*)d_in[3];
  const float* Wk  = (const float*)d_in[4];
  const float* bk  = (const float*)d_in[5];
  const float* Wv  = (const float*)d_in[6];
  const float* bv  = (const float*)d_in[7];
  const float* Wo  = (const float*)d_in[8];
  const float* bo  = (const float*)d_in[9];
  const float* W1  = (const float*)d_in[10];
  const float* b1  = (const float*)d_in[11];
  const float* W2  = (const float*)d_in[12];
  const float* b2  = (const float*)d_in[13];
  const float* g1  = (const float*)d_in[14];
  const float* be1 = (const float*)d_in[15];
  const float* g2  = (const float*)d_in[16];
  const float* be2 = (const float*)d_in[17];
  float* out = (float*)d_out;
  char* ws = (char*)d_ws;

  // ---- workspace layout (bytes), total 70,778,880 (~67.5 MB) ----
  constexpr size_t OFF_XB    = 0;          // 4096x768  bf16 (xb; attb alias after QKV)
  constexpr size_t OFF_WTQKV = 6291456;    // 2304x768  bf16 (dead after QKV GEMM)
  constexpr size_t OFF_VTILE = 6291456;    // [48][16][64] f32 overlays dead wt_qkv
  constexpr size_t OFF_WTO   = 9830400;    // 768x768   bf16 (dead after Wo GEMM)
  constexpr size_t OFF_Q     = 11010048;   // [48][1024][64] bf16 (dead after attn)
  constexpr size_t OFF_K     = 17301504;
  constexpr size_t OFF_VT    = 23592960;   // [48][64][1024] bf16 (dead after attn)
  constexpr size_t OFF_FF1   = 0;          // 4096x3072 bf16 overlays transient pool
  // Long-lived:
  constexpr size_t OFF_WT1   = 29884416;   // 3072x768  bf16
  constexpr size_t OFF_WT2   = 34603008;   // 768x3072  bf16
  constexpr size_t OFF_Y     = 39321600;   // 4096x768  f32 (y1, then y2)
  constexpr size_t OFF_X1    = 51904512;   // 4096x768  f32
  constexpr size_t OFF_X1B   = 64487424;   // 4096x768  bf16

  short* xb     = (short*)(ws + OFF_XB);
  short* attb   = (short*)(ws + OFF_XB);
  short* wt_qkv = (short*)(ws + OFF_WTQKV);
  float* vtile  = (float*)(ws + OFF_VTILE);
  short* wt_o   = (short*)(ws + OFF_WTO);
  short* wt_1   = (short*)(ws + OFF_WT1);
  short* wt_2   = (short*)(ws + OFF_WT2);
  short* qb     = (short*)(ws + OFF_Q);
  short* kb     = (short*)(ws + OFF_K);
  short* vt     = (short*)(ws + OFF_VT);
  float* y1     = (float*)(ws + OFF_Y);
  float* y2     = (float*)(ws + OFF_Y);
  float* x1     = (float*)(ws + OFF_X1);
  short* x1b    = (short*)(ws + OFF_X1B);
  short* ff1    = (short*)(ws + OFF_FF1);

  dim3 tb(32, 8);
  cvt_f32_bf16<<<3072, 256, 0, stream>>>(x, xb, Mn * En);
  transpose_w<<<dim3(24, 24), tb, 0, stream>>>(Wq, wt_qkv,              768, 768);
  transpose_w<<<dim3(24, 24), tb, 0, stream>>>(Wk, wt_qkv + 768 * 768,  768, 768);
  transpose_w<<<dim3(24, 24), tb, 0, stream>>>(Wv, wt_qkv + 1536 * 768, 768, 768);
  transpose_w<<<dim3(24, 24), tb, 0, stream>>>(Wo, wt_o, 768, 768);
  transpose_w<<<dim3(96, 24), tb, 0, stream>>>(W1, wt_1, 768, 3072);
  transpose_w<<<dim3(24, 96), tb, 0, stream>>>(W2, wt_2, 3072, 768);

  // QKV: 128x128, single-buffer m97 loop (32KB LDS, 3 blk/CU target)
  gemm_bt<128, 128, 1, 3, 0><<<dim3(18, 32), 256, 0, stream>>>(xb, wt_qkv, Mn, 2304, 768,
      nullptr, nullptr, bq, bk, bv, qb, kb, vt);
  vtile_sum<<<48, 256, 0, stream>>>(vt, vtile);
  attn_kernel<<<dim3(48, 16), 256, 0, stream>>>(qb, kb, vt, vtile, attb);
  // Wo: 64x64 double-buffer (32KB LDS, no occupancy cost), grid 768
  gemm_bt<64, 64, 0, 4, 1><<<dim3(12, 64), 256, 0, stream>>>(attb, wt_o, Mn, 768, 768,
      y1, nullptr, nullptr, nullptr, nullptr, nullptr, nullptr, nullptr);
  ln_kernel<<<Mn, 256, 0, stream>>>(x, y1, bo, g1, be1, x1, x1b);
  // FF1: 128x128, single-buffer m97 loop (32KB LDS, 3 blk/CU)
  gemm_bt<128, 128, 2, 3, 0><<<dim3(24, 32), 256, 0, stream>>>(x1b, wt_1, Mn, 3072, 768,
      nullptr, ff1, b1, nullptr, nullptr, nullptr, nullptr, nullptr);
  // FF2: 64x64 double-buffer, grid 768
  gemm_bt<64, 64, 0, 4, 1><<<dim3(12, 64), 256, 0, stream>>>(ff1, wt_2, Mn, 768, 3072,
      y2, nullptr, nullptr, nullptr, nullptr, nullptr, nullptr, nullptr);
  ln_kernel<<<Mn, 256, 0, stream>>>(x1, y2, b2, g2, be2, out, nullptr);
}

// Round 11
// 272.156 us; speedup vs baseline: 1.3762x; 1.0636x over previous
//
#include <hip/hip_runtime.h>
#include <hip/hip_bf16.h>

// ---------------- problem constants ----------------
constexpr int Bn = 4, Sn = 1024, En = 768, Hn = 12, Fn = 3072, Dn = 64;
constexpr int Mn = Bn * Sn;  // 4096 rows

typedef __attribute__((ext_vector_type(8))) short bf16x8;
typedef __attribute__((ext_vector_type(4))) float f32x4;

__device__ __forceinline__ short f2bs(float f) {
  unsigned u = __builtin_bit_cast(unsigned, f);
  unsigned r = (u + 0x7fffu + ((u >> 16) & 1u)) >> 16;  // RNE
  return (short)(r & 0xffffu);
}

__device__ __forceinline__ float bs2f(short s) {
  unsigned u = ((unsigned)(unsigned short)s) << 16;
  return __builtin_bit_cast(float, u);
}

__device__ __forceinline__ void gload16(const void* g, void* l) {
  __builtin_amdgcn_global_load_lds(
      (const __attribute__((address_space(1))) void*)g,
      (__attribute__((address_space(3))) void*)l, 16, 0, 0);
}

// ---------------- fused prep: x cvt + all 6 weight transposes (1 dispatch) ----
// blocks [0,3072): f32->bf16 cvt of x (4 elem/thread, exact coverage)
// blocks [3072,9984): 32x32 transpose tiles, W [K][N] f32 -> Wt [N][K] bf16
__global__ __launch_bounds__(256) void prep_all(
    const float* __restrict__ x, short* __restrict__ xb,
    const float* __restrict__ Wq, const float* __restrict__ Wk,
    const float* __restrict__ Wv, const float* __restrict__ Wo,
    const float* __restrict__ W1, const float* __restrict__ W2,
    short* __restrict__ wt_qkv, short* __restrict__ wt_o,
    short* __restrict__ wt_1, short* __restrict__ wt_2) {
  int blk = blockIdx.x;
  if (blk < 3072) {
    int i = (blk * 256 + threadIdx.x) * 4;
    float4 f = *(const float4*)(x + i);
    short4 o;
    o.x = f2bs(f.x); o.y = f2bs(f.y); o.z = f2bs(f.z); o.w = f2bs(f.w);
    *(short4*)(xb + i) = o;
    return;
  }
  blk -= 3072;
  const float* W; short* Wt; int K, N, nbx;
  if (blk < 576)       { W = Wq; Wt = wt_qkv;             K = 768;  N = 768;  nbx = 24; }
  else if (blk < 1152) { W = Wk; Wt = wt_qkv + 768 * 768; K = 768;  N = 768;  nbx = 24; blk -= 576; }
  else if (blk < 1728) { W = Wv; Wt = wt_qkv + 1536 * 768;K = 768;  N = 768;  nbx = 24; blk -= 1152; }
  else if (blk < 2304) { W = Wo; Wt = wt_o;               K = 768;  N = 768;  nbx = 24; blk -= 1728; }
  else if (blk < 4608) { W = W1; Wt = wt_1;               K = 768;  N = 3072; nbx = 96; blk -= 2304; }
  else                 { W = W2; Wt = wt_2;               K = 3072; N = 768;  nbx = 24; blk -= 4608; }
  int bx = (blk % nbx) * 32, by = (blk / nbx) * 32;
  __shared__ float t[32][33];
  int tx = threadIdx.x & 31, ty = threadIdx.x >> 5;
#pragma unroll
  for (int i = ty; i < 32; i += 8)
    t[i][tx] = W[(size_t)(by + i) * N + bx + tx];
  __syncthreads();
#pragma unroll
  for (int i = ty; i < 32; i += 8)
    Wt[(size_t)(bx + i) * K + by + tx] = f2bs(t[tx][i]);
}

// per-(bh, 64-tile) V column sums: Vtile[bh][kt][d] = sum_{s in tile kt} V[bh][s][d]
__global__ __launch_bounds__(256) void vtile_sum(
    const short* __restrict__ Vt, float* __restrict__ Vtile) {
  int bh = blockIdx.x;
  int d = threadIdx.x & 63, g = threadIdx.x >> 6;  // g = 0..3
#pragma unroll
  for (int i = 0; i < 4; ++i) {
    int kt = g * 4 + i;
    float s = 0.f;
    const short* p = Vt + ((size_t)bh * Dn + d) * Sn + kt * 64;
#pragma unroll
    for (int c = 0; c < 8; ++c) {
      bf16x8 v = *(const bf16x8*)(p + c * 8);
#pragma unroll
      for (int e = 0; e < 8; ++e) s += bs2f(v[e]);
    }
    Vtile[((size_t)bh * 16 + kt) * 64 + d] = s;
  }
}

// ---------------- GEMM: C[M,N] = A[M,K](bf16) * Bt[N,K]^T(bf16) ----------------
// Tiles: BM x BN, 2x2 waves, BK=64. DBUF=0: m97 single-buffer 2-barrier loop
// (32KB LDS -> 3+ blocks/CU; implicit wave-level overlap does latency hiding,
// per m114/m132 evidence). DBUF=1: 1-barrier double-buffer (only where the
// extra LDS doesn't cut residency, i.e. 64^2 tiles). XCD-chunked swizzle.
// MODE 0: Cf = raw f32    MODE 1: QKV scatter (+bias) -> Qo/Ko/Vto bf16
// MODE 2: Cb = bf16 gelu(acc + bias0)
template <int BM, int BN, int MODE, int OCC, int DBUF>
__global__ __launch_bounds__(256, OCC) void gemm_bt(
    const short* __restrict__ A, const short* __restrict__ Bt,
    int M, int N, int K,
    float* __restrict__ Cf, short* __restrict__ Cb,
    const float* __restrict__ bias0, const float* __restrict__ bias1,
    const float* __restrict__ bias2,
    short* __restrict__ Qo, short* __restrict__ Ko, short* __restrict__ Vto) {
  constexpr int WM = BM / 2, WN = BN / 2;
  constexpr int MR = WM / 16, NR = WN / 16;
  constexpr int NB = DBUF + 1;
  __shared__ short Asm[NB][BM * 64];
  __shared__ short Bsm[NB][BN * 64];
  const int tid = threadIdx.x, wv = tid >> 6, ln = tid & 63;

  // XCD-chunked swizzle: hardware round-robins dispatch index over 8 XCDs;
  // remap so each XCD gets a CONTIGUOUS logical chunk (shared A-strips in L2).
  const int gx = gridDim.x;
  const int nwg = gx * gridDim.y;
  const int d = blockIdx.y * gx + blockIdx.x;
  const int l = (d & 7) * (nwg >> 3) + (d >> 3);
  const int m0 = (l / gx) * BM, n0 = (l % gx) * BN;

  const int wm = (wv >> 1) * WM, wn = (wv & 1) * WN;
  f32x4 acc[MR][NR] = {};

  // stage one K-step tile pair: pre-swizzled global source -> linear LDS dest
  auto stage = [&](int bi, int k0) {
#pragma unroll
    for (int p = 0; p < BM / 32; ++p) {
      int off = p * 4096 + wv * 1024 + ln * 16;  // byte offset in A tile
      int r = off >> 7, sl = (off >> 4) & 7, ss = sl ^ (r & 7);
      gload16(A + (size_t)(m0 + r) * K + k0 + ss * 8,
              (char*)Asm[bi] + p * 4096 + wv * 1024);
    }
#pragma unroll
    for (int p = 0; p < BN / 32; ++p) {
      int off = p * 4096 + wv * 1024 + ln * 16;
      int r = off >> 7, sl = (off >> 4) & 7, ss = sl ^ (r & 7);
      gload16(Bt + (size_t)(n0 + r) * K + k0 + ss * 8,
              (char*)Bsm[bi] + p * 4096 + wv * 1024);
    }
  };

  auto compute = [&](int bi) {
    bf16x8 av[2][MR], bv[2][NR];
#pragma unroll
    for (int kk = 0; kk < 2; ++kk) {
#pragma unroll
      for (int i = 0; i < MR; ++i) {
        int ra = wm + i * 16 + (ln & 15);
        int sa = (kk * 4 + (ln >> 4)) ^ (ra & 7);
        av[kk][i] = *(const bf16x8*)((const char*)Asm[bi] + ra * 128 + sa * 16);
      }
#pragma unroll
      for (int i = 0; i < NR; ++i) {
        int rb = wn + i * 16 + (ln & 15);
        int sb = (kk * 4 + (ln >> 4)) ^ (rb & 7);
        bv[kk][i] = *(const bf16x8*)((const char*)Bsm[bi] + rb * 128 + sb * 16);
      }
    }
#pragma unroll
    for (int kk = 0; kk < 2; ++kk)
#pragma unroll
      for (int mi = 0; mi < MR; ++mi)
#pragma unroll
        for (int ni = 0; ni < NR; ++ni)
          acc[mi][ni] = __builtin_amdgcn_mfma_f32_16x16x32_bf16(
              av[kk][mi], bv[kk][ni], acc[mi][ni], 0, 0, 0);
  };

  const int nt = K >> 6;
  if constexpr (DBUF) {
    stage(0, 0);
    int buf = 0;
    for (int t = 0; t < nt; ++t) {
      __syncthreads();  // drains tile-t staging + guards buffer reuse
      if (t + 1 < nt) stage(buf ^ 1, (t + 1) * 64);
      compute(buf);
      buf ^= 1;
    }
  } else {
    for (int t = 0; t < nt; ++t) {
      stage(0, t * 64);
      __syncthreads();  // staging complete
      compute(0);
      __syncthreads();  // reads done before next-tile overwrite
    }
  }

  // C/D layout (m89-verified): col = lane&15, row = (lane>>4)*4 + j
#pragma unroll
  for (int mi = 0; mi < MR; ++mi)
#pragma unroll
    for (int ni = 0; ni < NR; ++ni)
#pragma unroll
      for (int j = 0; j < 4; ++j) {
        int row = m0 + wm + mi * 16 + (ln >> 4) * 4 + j;
        int col = n0 + wn + ni * 16 + (ln & 15);
        float v = acc[mi][ni][j];
        if constexpr (MODE == 0) {
          Cf[(size_t)row * N + col] = v;
        } else if constexpr (MODE == 1) {
          int part = col / 768;  // tile cols never straddle parts
          int nn = col - part * 768;
          int h = nn >> 6, dd = nn & 63;
          int b = row >> 10, s = row & 1023;
          size_t bh = (size_t)(b * Hn + h);
          float bias = (part == 0) ? bias0[nn] : (part == 1) ? bias1[nn] : bias2[nn];
          short o = f2bs(v + bias);
          if (part == 0)       Qo[(bh * Sn + s) * Dn + dd] = o;
          else if (part == 1)  Ko[(bh * Sn + s) * Dn + dd] = o;
          else                 Vto[(bh * Dn + dd) * Sn + s] = o;  // pre-transposed V
        } else {
          float u = v + bias0[col];
          float gl = 0.5f * u * (1.0f + erff(u * 0.70710678118654752f));
          Cb[(size_t)row * N + col] = f2bs(gl);
        }
      }
}

// ---------------- sparse flash attention, multiplicative Sierpinski mask ----------------
// Tile (qt,kt) fully masked unless qt&kt==0 -> only 81/256 tiles computed.
// Fixed softmax shift m=0 (scores bounded): p=exp(s'), purely additive, so
// skipped tiles contribute 64 to denom and Vtile-sums to numerator (epilogue).
// Q,K: [BH][S][D] bf16   Vt: [BH][D][S] bf16   Vtile: [BH][16][64] f32
__device__ const int qt_order[16] = {0, 1, 2, 4, 8, 3, 5, 6, 9, 10, 12, 7, 11, 13, 14, 15};

__global__ __launch_bounds__(256, 2) void attn_kernel(
    const short* __restrict__ Qb, const short* __restrict__ Kb,
    const short* __restrict__ Vt, const float* __restrict__ Vtile,
    short* __restrict__ att) {
  __shared__ short Ksm[2][64 * 64];
  __shared__ short Vsm[2][64 * 64];
  __shared__ short P_lds[4][16 * 64];
  const int tid = threadIdx.x, wv = tid >> 6, ln = tid & 63;
  const int bh = blockIdx.x;              // 48
  const int qt = qt_order[blockIdx.y];    // heavy (qt=0) blocks first
  const int q0 = qt * 64 + wv * 16;
  const int b = bh / Hn, h = bh - b * Hn;
  const int notqt = (~qt) & 15;
  const int nv = 1 << __popc(notqt);      // visited tiles

  // Q fragment (A-operand), 16 rows per wave
  const size_t qoff = ((size_t)bh * Sn + q0) * Dn;
  bf16x8 aq[2];
#pragma unroll
  for (int kk = 0; kk < 2; ++kk)
    aq[kk] = *(const bf16x8*)(Qb + qoff + (size_t)(ln & 15) * Dn + kk * 32 + (ln >> 4) * 8);

  f32x4 o_acc[4] = {};
  float l_run[4] = {0.f, 0.f, 0.f, 0.f};
  short* Pw = (short*)&P_lds[wv][0];

  // stage K-tile + V-tile (8KB each) into LDS buf; pre-swizzled source,
  // linear LDS dest, swizzled read (rule #21 involution)
  auto stage = [&](int bufi, int kt) {
#pragma unroll
    for (int i = 0; i < 2; ++i) {
      int off = i * 4096 + wv * 1024 + ln * 16;
      int r = off >> 7, sl = (off >> 4) & 7, ss = sl ^ (r & 7);
      gload16(Kb + ((size_t)bh * Sn + (size_t)kt * 64 + r) * Dn + ss * 8,
              (char*)Ksm[bufi] + i * 4096 + wv * 1024);
      gload16(Vt + ((size_t)bh * Dn + r) * Sn + (size_t)kt * 64 + ss * 8,
              (char*)Vsm[bufi] + i * 4096 + wv * 1024);
    }
  };

  stage(0, 0);  // kt=0 always visited (0 & qt == 0)
  __syncthreads();
  int buf = 0, kt = 0;
  while (true) {
    const int ktn = ((kt | qt) + 1) & notqt;  // next visited tile; 0 => done
    if (ktn) stage(buf ^ 1, ktn);

    // QK^T from LDS
    f32x4 s_acc[4] = {};
#pragma unroll
    for (int kk = 0; kk < 2; ++kk)
#pragma unroll
      for (int ni = 0; ni < 4; ++ni) {
        int rb = ni * 16 + (ln & 15);
        int sb = (kk * 4 + (ln >> 4)) ^ (rb & 7);
        bf16x8 bk = *(const bf16x8*)((const char*)Ksm[buf] + rb * 128 + sb * 16);
        s_acc[ni] = __builtin_amdgcn_mfma_f32_16x16x32_bf16(aq[kk], bk, s_acc[ni], 0, 0, 0);
      }

    // mask + exp (fixed m=0), deferred per-lane denom, P -> LDS
#pragma unroll
    for (int ni = 0; ni < 4; ++ni)
#pragma unroll
      for (int j = 0; j < 4; ++j) {
        int q = q0 + (ln >> 4) * 4 + j;
        int k = kt * 64 + ni * 16 + (ln & 15);
        float p = ((q & k) == 0) ? __expf(s_acc[ni][j] * 0.125f) : 1.0f;
        l_run[j] += p;
        int prow = (ln >> 4) * 4 + j;
        int pcol = ni * 16 + (ln & 15);
        int sw = (pcol >> 3) ^ (prow & 7);
        Pw[prow * 64 + sw * 8 + (pcol & 7)] = f2bs(p);
      }

    // PV from LDS
#pragma unroll
    for (int kk = 0; kk < 2; ++kk) {
      int prow = ln & 15;
      int swp = (kk * 4 + (ln >> 4)) ^ (prow & 7);
      bf16x8 ap = *(const bf16x8*)(Pw + prow * 64 + swp * 8);
#pragma unroll
      for (int di = 0; di < 4; ++di) {
        int rv = di * 16 + (ln & 15);
        int sv = (kk * 4 + (ln >> 4)) ^ (rv & 7);
        bf16x8 bv = *(const bf16x8*)((const char*)Vsm[buf] + rv * 128 + sv * 16);
        o_acc[di] = __builtin_amdgcn_mfma_f32_16x16x32_bf16(ap, bv, o_acc[di], 0, 0, 0);
      }
    }

    __syncthreads();  // drains vmcnt (next tile staged) + guards buf reuse
    buf ^= 1;
    if (!ktn) break;
    kt = ktn;
  }

  // epilogue: skipped-tile corrections
  float vc[4] = {0.f, 0.f, 0.f, 0.f};
  for (int t = 0; t < 16; ++t)
    if (qt & t) {
#pragma unroll
      for (int di = 0; di < 4; ++di)
        vc[di] += Vtile[((size_t)bh * 16 + t) * 64 + di * 16 + (ln & 15)];
    }
  const float skip_l = 64.0f * (float)(16 - nv);
  float ltot[4];
#pragma unroll
  for (int j = 0; j < 4; ++j) {
    float l = l_run[j];
#pragma unroll
    for (int o = 1; o < 16; o <<= 1) l += __shfl_xor(l, o);
    ltot[j] = l + skip_l;
  }
#pragma unroll
  for (int di = 0; di < 4; ++di)
#pragma unroll
    for (int j = 0; j < 4; ++j) {
      int s = q0 + (ln >> 4) * 4 + j;
      int e = h * 64 + di * 16 + (ln & 15);
      att[((size_t)b * Sn + s) * En + e] = f2bs((o_acc[di][j] + vc[di]) / ltot[j]);
    }
}

// ---------------- residual + bias + LayerNorm (two-pass, f32) ----------------
__device__ __forceinline__ float block_reduce_sum(float v, float* sbuf) {
#pragma unroll
  for (int o = 32; o > 0; o >>= 1) v += __shfl_down(v, o);
  int wv = threadIdx.x >> 6, ln = threadIdx.x & 63;
  __syncthreads();
  if (ln == 0) sbuf[wv] = v;
  __syncthreads();
  return sbuf[0] + sbuf[1] + sbuf[2] + sbuf[3];
}

__global__ __launch_bounds__(256) void ln_kernel(
    const float* __restrict__ xr, const float* __restrict__ yr,
    const float* __restrict__ bias, const float* __restrict__ g,
    const float* __restrict__ be, float* __restrict__ outf,
    short* __restrict__ outb) {
  __shared__ float sbuf[4];
  int row = blockIdx.x, tid = threadIdx.x;
  size_t base = (size_t)row * En;
  float u[3];
  float s = 0.f;
#pragma unroll
  for (int t = 0; t < 3; ++t) {
    int i = tid + t * 256;
    u[t] = xr[base + i] + yr[base + i] + bias[i];
    s += u[t];
  }
  s = block_reduce_sum(s, sbuf);
  float mean = s * (1.0f / En);
  float s2 = 0.f;
#pragma unroll
  for (int t = 0; t < 3; ++t) { float d = u[t] - mean; s2 += d * d; }
  s2 = block_reduce_sum(s2, sbuf);
  float rstd = rsqrtf(s2 * (1.0f / En) + 1e-5f);
#pragma unroll
  for (int t = 0; t < 3; ++t) {
    int i = tid + t * 256;
    float o = (u[t] - mean) * rstd * g[i] + be[i];
    outf[base + i] = o;
    if (outb) outb[base + i] = f2bs(o);
  }
}

// ---------------- launch ----------------
extern "C" void kernel_launch(void* const* d_in, const int* in_sizes, int n_in,
                              void* d_out, int out_size, void* d_ws, size_t ws_size,
                              hipStream_t stream) {
  const float* x   = (const float*)d_in[0];
  const float* Wq  = (const float*)d_in[2];
  const float* bq  = (const float*)d_in[3];
  const float* Wk  = (const float*)d_in[4];
  const float* bk  = (const float*)d_in[5];
  const float* Wv  = (const float*)d_in[6];
  const float* bv  = (const float*)d_in[7];
  const float* Wo  = (const float*)d_in[8];
  const float* bo  = (const float*)d_in[9];
  const float* W1  = (const float*)d_in[10];
  const float* b1  = (const float*)d_in[11];
  const float* W2  = (const float*)d_in[12];
  const float* b2  = (const float*)d_in[13];
  const float* g1  = (const float*)d_in[14];
  const float* be1 = (const float*)d_in[15];
  const float* g2  = (const float*)d_in[16];
  const float* be2 = (const float*)d_in[17];
  float* out = (float*)d_out;
  char* ws = (char*)d_ws;

  // ---- workspace layout (bytes), total 70,778,880 (~67.5 MB) ----
  constexpr size_t OFF_XB    = 0;          // 4096x768  bf16 (xb; attb alias after QKV)
  constexpr size_t OFF_WTQKV = 6291456;    // 2304x768  bf16 (dead after QKV GEMM)
  constexpr size_t OFF_VTILE = 6291456;    // [48][16][64] f32 overlays dead wt_qkv
  constexpr size_t OFF_WTO   = 9830400;    // 768x768   bf16 (dead after Wo GEMM)
  constexpr size_t OFF_Q     = 11010048;   // [48][1024][64] bf16 (dead after attn)
  constexpr size_t OFF_K     = 17301504;
  constexpr size_t OFF_VT    = 23592960;   // [48][64][1024] bf16 (dead after attn)
  constexpr size_t OFF_FF1   = 0;          // 4096x3072 bf16 overlays transient pool
  // Long-lived:
  constexpr size_t OFF_WT1   = 29884416;   // 3072x768  bf16
  constexpr size_t OFF_WT2   = 34603008;   // 768x3072  bf16
  constexpr size_t OFF_Y     = 39321600;   // 4096x768  f32 (y1, then y2)
  constexpr size_t OFF_X1    = 51904512;   // 4096x768  f32
  constexpr size_t OFF_X1B   = 64487424;   // 4096x768  bf16

  short* xb     = (short*)(ws + OFF_XB);
  short* attb   = (short*)(ws + OFF_XB);
  short* wt_qkv = (short*)(ws + OFF_WTQKV);
  float* vtile  = (float*)(ws + OFF_VTILE);
  short* wt_o   = (short*)(ws + OFF_WTO);
  short* wt_1   = (short*)(ws + OFF_WT1);
  short* wt_2   = (short*)(ws + OFF_WT2);
  short* qb     = (short*)(ws + OFF_Q);
  short* kb     = (short*)(ws + OFF_K);
  short* vt     = (short*)(ws + OFF_VT);
  float* y1     = (float*)(ws + OFF_Y);
  float* y2     = (float*)(ws + OFF_Y);
  float* x1     = (float*)(ws + OFF_X1);
  short* x1b    = (short*)(ws + OFF_X1B);
  short* ff1    = (short*)(ws + OFF_FF1);

  // fused prep: 1 dispatch replaces cvt + 6 transposes
  prep_all<<<9984, 256, 0, stream>>>(x, xb, Wq, Wk, Wv, Wo, W1, W2,
                                     wt_qkv, wt_o, wt_1, wt_2);

  // QKV: 128x128, single-buffer m97 loop (32KB LDS, 3 blk/CU target)
  gemm_bt<128, 128, 1, 3, 0><<<dim3(18, 32), 256, 0, stream>>>(xb, wt_qkv, Mn, 2304, 768,
      nullptr, nullptr, bq, bk, bv, qb, kb, vt);
  vtile_sum<<<48, 256, 0, stream>>>(vt, vtile);
  attn_kernel<<<dim3(48, 16), 256, 0, stream>>>(qb, kb, vt, vtile, attb);
  // Wo: 64x64 double-buffer (32KB LDS, no occupancy cost), grid 768
  gemm_bt<64, 64, 0, 4, 1><<<dim3(12, 64), 256, 0, stream>>>(attb, wt_o, Mn, 768, 768,
      y1, nullptr, nullptr, nullptr, nullptr, nullptr, nullptr, nullptr);
  ln_kernel<<<Mn, 256, 0, stream>>>(x, y1, bo, g1, be1, x1, x1b);
  // FF1: 128x128, single-buffer m97 loop (32KB LDS, 3 blk/CU)
  gemm_bt<128, 128, 2, 3, 0><<<dim3(24, 32), 256, 0, stream>>>(x1b, wt_1, Mn, 3072, 768,
      nullptr, ff1, b1, nullptr, nullptr, nullptr, nullptr, nullptr);
  // FF2: 64x64 double-buffer, grid 768
  gemm_bt<64, 64, 0, 4, 1><<<dim3(12, 64), 256, 0, stream>>>(ff1, wt_2, Mn, 768, 3072,
      y2, nullptr, nullptr, nullptr, nullptr, nullptr, nullptr, nullptr);
  ln_kernel<<<Mn, 256, 0, stream>>>(x1, y2, b2, g2, be2, out, nullptr);
}

// Round 12
// 269.568 us; speedup vs baseline: 1.3894x; 1.0096x over previous
//
#include <hip/hip_runtime.h>
#include <hip/hip_bf16.h>

// ---------------- problem constants ----------------
constexpr int Bn = 4, Sn = 1024, En = 768, Hn = 12, Fn = 3072, Dn = 64;
constexpr int Mn = Bn * Sn;  // 4096 rows

typedef __attribute__((ext_vector_type(8))) short bf16x8;
typedef __attribute__((ext_vector_type(4))) float f32x4;

__device__ __forceinline__ short f2bs(float f) {
  unsigned u = __builtin_bit_cast(unsigned, f);
  unsigned r = (u + 0x7fffu + ((u >> 16) & 1u)) >> 16;  // RNE
  return (short)(r & 0xffffu);
}

__device__ __forceinline__ float bs2f(short s) {
  unsigned u = ((unsigned)(unsigned short)s) << 16;
  return __builtin_bit_cast(float, u);
}

__device__ __forceinline__ void gload16(const void* g, void* l) {
  __builtin_amdgcn_global_load_lds(
      (const __attribute__((address_space(1))) void*)g,
      (__attribute__((address_space(3))) void*)l, 16, 0, 0);
}

// ---------------- fused prep: x cvt + all 6 weight transposes (1 dispatch) ----
__global__ __launch_bounds__(256) void prep_all(
    const float* __restrict__ x, short* __restrict__ xb,
    const float* __restrict__ Wq, const float* __restrict__ Wk,
    const float* __restrict__ Wv, const float* __restrict__ Wo,
    const float* __restrict__ W1, const float* __restrict__ W2,
    short* __restrict__ wt_qkv, short* __restrict__ wt_o,
    short* __restrict__ wt_1, short* __restrict__ wt_2) {
  int blk = blockIdx.x;
  if (blk < 3072) {
    int i = (blk * 256 + threadIdx.x) * 4;
    float4 f = *(const float4*)(x + i);
    short4 o;
    o.x = f2bs(f.x); o.y = f2bs(f.y); o.z = f2bs(f.z); o.w = f2bs(f.w);
    *(short4*)(xb + i) = o;
    return;
  }
  blk -= 3072;
  const float* W; short* Wt; int K, N, nbx;
  if (blk < 576)       { W = Wq; Wt = wt_qkv;             K = 768;  N = 768;  nbx = 24; }
  else if (blk < 1152) { W = Wk; Wt = wt_qkv + 768 * 768; K = 768;  N = 768;  nbx = 24; blk -= 576; }
  else if (blk < 1728) { W = Wv; Wt = wt_qkv + 1536 * 768;K = 768;  N = 768;  nbx = 24; blk -= 1152; }
  else if (blk < 2304) { W = Wo; Wt = wt_o;               K = 768;  N = 768;  nbx = 24; blk -= 1728; }
  else if (blk < 4608) { W = W1; Wt = wt_1;               K = 768;  N = 3072; nbx = 96; blk -= 2304; }
  else                 { W = W2; Wt = wt_2;               K = 3072; N = 768;  nbx = 24; blk -= 4608; }
  int bx = (blk % nbx) * 32, by = (blk / nbx) * 32;
  __shared__ float t[32][33];
  int tx = threadIdx.x & 31, ty = threadIdx.x >> 5;
#pragma unroll
  for (int i = ty; i < 32; i += 8)
    t[i][tx] = W[(size_t)(by + i) * N + bx + tx];
  __syncthreads();
#pragma unroll
  for (int i = ty; i < 32; i += 8)
    Wt[(size_t)(bx + i) * K + by + tx] = f2bs(t[tx][i]);
}

// per-(bh, 64-tile) V column sums: Vtile[bh][kt][d] = sum_{s in tile kt} V[bh][s][d]
__global__ __launch_bounds__(256) void vtile_sum(
    const short* __restrict__ Vt, float* __restrict__ Vtile) {
  int bh = blockIdx.x;
  int d = threadIdx.x & 63, g = threadIdx.x >> 6;  // g = 0..3
#pragma unroll
  for (int i = 0; i < 4; ++i) {
    int kt = g * 4 + i;
    float s = 0.f;
    const short* p = Vt + ((size_t)bh * Dn + d) * Sn + kt * 64;
#pragma unroll
    for (int c = 0; c < 8; ++c) {
      bf16x8 v = *(const bf16x8*)(p + c * 8);
#pragma unroll
      for (int e = 0; e < 8; ++e) s += bs2f(v[e]);
    }
    Vtile[((size_t)bh * 16 + kt) * 64 + d] = s;
  }
}

// ---------------- GEMM: C[M,N] = A[M,K](bf16) * Bt[N,K]^T(bf16) ----------------
// Tiles: BM x BN, 2x2 waves, BK=64. DBUF=0: m97 single-buffer 2-barrier loop.
// DBUF=1: 1-barrier double-buffer (only where extra LDS doesn't cut residency).
// XCD-chunked swizzle (grid % 8 == 0 -> bijective).
// MODE 0: Cf = raw f32    MODE 1: QKV scatter (+bias) -> Qo/Ko/Vto bf16
// MODE 2: Cb = bf16 gelu(acc + bias0)
template <int BM, int BN, int MODE, int OCC, int DBUF>
__global__ __launch_bounds__(256, OCC) void gemm_bt(
    const short* __restrict__ A, const short* __restrict__ Bt,
    int M, int N, int K,
    float* __restrict__ Cf, short* __restrict__ Cb,
    const float* __restrict__ bias0, const float* __restrict__ bias1,
    const float* __restrict__ bias2,
    short* __restrict__ Qo, short* __restrict__ Ko, short* __restrict__ Vto) {
  constexpr int WM = BM / 2, WN = BN / 2;
  constexpr int MR = WM / 16, NR = WN / 16;
  constexpr int NB = DBUF + 1;
  __shared__ short Asm[NB][BM * 64];
  __shared__ short Bsm[NB][BN * 64];
  const int tid = threadIdx.x, wv = tid >> 6, ln = tid & 63;

  const int gx = gridDim.x;
  const int nwg = gx * gridDim.y;
  const int d = blockIdx.y * gx + blockIdx.x;
  const int l = (d & 7) * (nwg >> 3) + (d >> 3);
  const int m0 = (l / gx) * BM, n0 = (l % gx) * BN;

  const int wm = (wv >> 1) * WM, wn = (wv & 1) * WN;
  f32x4 acc[MR][NR] = {};

  auto stage = [&](int bi, int k0) {
#pragma unroll
    for (int p = 0; p < BM / 32; ++p) {
      int off = p * 4096 + wv * 1024 + ln * 16;
      int r = off >> 7, sl = (off >> 4) & 7, ss = sl ^ (r & 7);
      gload16(A + (size_t)(m0 + r) * K + k0 + ss * 8,
              (char*)Asm[bi] + p * 4096 + wv * 1024);
    }
#pragma unroll
    for (int p = 0; p < BN / 32; ++p) {
      int off = p * 4096 + wv * 1024 + ln * 16;
      int r = off >> 7, sl = (off >> 4) & 7, ss = sl ^ (r & 7);
      gload16(Bt + (size_t)(n0 + r) * K + k0 + ss * 8,
              (char*)Bsm[bi] + p * 4096 + wv * 1024);
    }
  };

  auto compute = [&](int bi) {
    bf16x8 av[2][MR], bv[2][NR];
#pragma unroll
    for (int kk = 0; kk < 2; ++kk) {
#pragma unroll
      for (int i = 0; i < MR; ++i) {
        int ra = wm + i * 16 + (ln & 15);
        int sa = (kk * 4 + (ln >> 4)) ^ (ra & 7);
        av[kk][i] = *(const bf16x8*)((const char*)Asm[bi] + ra * 128 + sa * 16);
      }
#pragma unroll
      for (int i = 0; i < NR; ++i) {
        int rb = wn + i * 16 + (ln & 15);
        int sb = (kk * 4 + (ln >> 4)) ^ (rb & 7);
        bv[kk][i] = *(const bf16x8*)((const char*)Bsm[bi] + rb * 128 + sb * 16);
      }
    }
#pragma unroll
    for (int kk = 0; kk < 2; ++kk)
#pragma unroll
      for (int mi = 0; mi < MR; ++mi)
#pragma unroll
        for (int ni = 0; ni < NR; ++ni)
          acc[mi][ni] = __builtin_amdgcn_mfma_f32_16x16x32_bf16(
              av[kk][mi], bv[kk][ni], acc[mi][ni], 0, 0, 0);
  };

  const int nt = K >> 6;
  if constexpr (DBUF) {
    stage(0, 0);
    int buf = 0;
    for (int t = 0; t < nt; ++t) {
      __syncthreads();
      if (t + 1 < nt) stage(buf ^ 1, (t + 1) * 64);
      compute(buf);
      buf ^= 1;
    }
  } else {
    for (int t = 0; t < nt; ++t) {
      stage(0, t * 64);
      __syncthreads();
      compute(0);
      __syncthreads();
    }
  }

  // C/D layout (m89-verified): col = lane&15, row = (lane>>4)*4 + j
#pragma unroll
  for (int mi = 0; mi < MR; ++mi)
#pragma unroll
    for (int ni = 0; ni < NR; ++ni)
#pragma unroll
      for (int j = 0; j < 4; ++j) {
        int row = m0 + wm + mi * 16 + (ln >> 4) * 4 + j;
        int col = n0 + wn + ni * 16 + (ln & 15);
        float v = acc[mi][ni][j];
        if constexpr (MODE == 0) {
          Cf[(size_t)row * N + col] = v;
        } else if constexpr (MODE == 1) {
          int part = col / 768;
          int nn = col - part * 768;
          int h = nn >> 6, dd = nn & 63;
          int b = row >> 10, s = row & 1023;
          size_t bh = (size_t)(b * Hn + h);
          float bias = (part == 0) ? bias0[nn] : (part == 1) ? bias1[nn] : bias2[nn];
          short o = f2bs(v + bias);
          if (part == 0)       Qo[(bh * Sn + s) * Dn + dd] = o;
          else if (part == 1)  Ko[(bh * Sn + s) * Dn + dd] = o;
          else                 Vto[(bh * Dn + dd) * Sn + s] = o;  // pre-transposed V
        } else {
          float u = v + bias0[col];
          float gl = 0.5f * u * (1.0f + erff(u * 0.70710678118654752f));
          Cb[(size_t)row * N + col] = f2bs(gl);
        }
      }
}

// ---------------- sparse flash attention, multiplicative Sierpinski mask ----------------
// Tile (qt,kt) computed only when qt&kt==0 (81/256). Fixed softmax shift m=0;
// skipped tiles contribute 64 to denom and Vtile-sums to numerator (epilogue).
// SINGLE-buffered K/V (LDS 24KB -> 5-6 blocks/CU; TLP hides L2-resident stage
// latency, same trade as the GEMM sbuf win in rounds 8-9).
__device__ const int qt_order[16] = {0, 1, 2, 4, 8, 3, 5, 6, 9, 10, 12, 7, 11, 13, 14, 15};

__global__ __launch_bounds__(256, 2) void attn_kernel(
    const short* __restrict__ Qb, const short* __restrict__ Kb,
    const short* __restrict__ Vt, const float* __restrict__ Vtile,
    short* __restrict__ att) {
  __shared__ short Ksm[64 * 64];
  __shared__ short Vsm[64 * 64];
  __shared__ short P_lds[4][16 * 64];
  const int tid = threadIdx.x, wv = tid >> 6, ln = tid & 63;
  const int bh = blockIdx.x;              // 48
  const int qt = qt_order[blockIdx.y];    // heavy (qt=0) blocks first
  const int q0 = qt * 64 + wv * 16;
  const int b = bh / Hn, h = bh - b * Hn;
  const int notqt = (~qt) & 15;
  const int nv = 1 << __popc(notqt);      // visited tiles

  const size_t qoff = ((size_t)bh * Sn + q0) * Dn;
  bf16x8 aq[2];
#pragma unroll
  for (int kk = 0; kk < 2; ++kk)
    aq[kk] = *(const bf16x8*)(Qb + qoff + (size_t)(ln & 15) * Dn + kk * 32 + (ln >> 4) * 8);

  f32x4 o_acc[4] = {};
  float l_run[4] = {0.f, 0.f, 0.f, 0.f};
  short* Pw = (short*)&P_lds[wv][0];

  auto stage = [&](int kt) {
#pragma unroll
    for (int i = 0; i < 2; ++i) {
      int off = i * 4096 + wv * 1024 + ln * 16;
      int r = off >> 7, sl = (off >> 4) & 7, ss = sl ^ (r & 7);
      gload16(Kb + ((size_t)bh * Sn + (size_t)kt * 64 + r) * Dn + ss * 8,
              (char*)Ksm + i * 4096 + wv * 1024);
      gload16(Vt + ((size_t)bh * Dn + r) * Sn + (size_t)kt * 64 + ss * 8,
              (char*)Vsm + i * 4096 + wv * 1024);
    }
  };

  int kt = 0;
  while (true) {
    stage(kt);
    __syncthreads();  // staging complete (vmcnt drained)

    // QK^T from LDS
    f32x4 s_acc[4] = {};
#pragma unroll
    for (int kk = 0; kk < 2; ++kk)
#pragma unroll
      for (int ni = 0; ni < 4; ++ni) {
        int rb = ni * 16 + (ln & 15);
        int sb = (kk * 4 + (ln >> 4)) ^ (rb & 7);
        bf16x8 bk = *(const bf16x8*)((const char*)Ksm + rb * 128 + sb * 16);
        s_acc[ni] = __builtin_amdgcn_mfma_f32_16x16x32_bf16(aq[kk], bk, s_acc[ni], 0, 0, 0);
      }

    // mask + exp (fixed m=0), deferred per-lane denom, P -> LDS (wave-private)
#pragma unroll
    for (int ni = 0; ni < 4; ++ni)
#pragma unroll
      for (int j = 0; j < 4; ++j) {
        int q = q0 + (ln >> 4) * 4 + j;
        int k = kt * 64 + ni * 16 + (ln & 15);
        float p = ((q & k) == 0) ? __expf(s_acc[ni][j] * 0.125f) : 1.0f;
        l_run[j] += p;
        int prow = (ln >> 4) * 4 + j;
        int pcol = ni * 16 + (ln & 15);
        int sw = (pcol >> 3) ^ (prow & 7);
        Pw[prow * 64 + sw * 8 + (pcol & 7)] = f2bs(p);
      }

    // PV from LDS
#pragma unroll
    for (int kk = 0; kk < 2; ++kk) {
      int prow = ln & 15;
      int swp = (kk * 4 + (ln >> 4)) ^ (prow & 7);
      bf16x8 ap = *(const bf16x8*)(Pw + prow * 64 + swp * 8);
#pragma unroll
      for (int di = 0; di < 4; ++di) {
        int rv = di * 16 + (ln & 15);
        int sv = (kk * 4 + (ln >> 4)) ^ (rv & 7);
        bf16x8 bv = *(const bf16x8*)((const char*)Vsm + rv * 128 + sv * 16);
        o_acc[di] = __builtin_amdgcn_mfma_f32_16x16x32_bf16(ap, bv, o_acc[di], 0, 0, 0);
      }
    }

    const int ktn = ((kt | qt) + 1) & notqt;  // next visited tile; 0 => done
    __syncthreads();  // reads done before next-tile overwrite
    if (!ktn) break;
    kt = ktn;
  }

  // epilogue: skipped-tile corrections
  float vc[4] = {0.f, 0.f, 0.f, 0.f};
  for (int t = 0; t < 16; ++t)
    if (qt & t) {
#pragma unroll
      for (int di = 0; di < 4; ++di)
        vc[di] += Vtile[((size_t)bh * 16 + t) * 64 + di * 16 + (ln & 15)];
    }
  const float skip_l = 64.0f * (float)(16 - nv);
  float ltot[4];
#pragma unroll
  for (int j = 0; j < 4; ++j) {
    float l = l_run[j];
#pragma unroll
    for (int o = 1; o < 16; o <<= 1) l += __shfl_xor(l, o);
    ltot[j] = l + skip_l;
  }
#pragma unroll
  for (int di = 0; di < 4; ++di)
#pragma unroll
    for (int j = 0; j < 4; ++j) {
      int s = q0 + (ln >> 4) * 4 + j;
      int e = h * 64 + di * 16 + (ln & 15);
      att[((size_t)b * Sn + s) * En + e] = f2bs((o_acc[di][j] + vc[di]) / ltot[j]);
    }
}

// ---------------- residual + bias + LayerNorm (vectorized: 192 thr, float4) ----
__global__ __launch_bounds__(192) void ln_kernel(
    const float* __restrict__ xr, const float* __restrict__ yr,
    const float* __restrict__ bias, const float* __restrict__ g,
    const float* __restrict__ be, float* __restrict__ outf,
    short* __restrict__ outb) {
  __shared__ float sbuf[3];
  const int row = blockIdx.x, tid = threadIdx.x;
  const int wv = tid >> 6, lnn = tid & 63;
  const size_t base = (size_t)row * En;
  const int i4 = tid * 4;

  float4 xv = *(const float4*)(xr + base + i4);
  float4 yv = *(const float4*)(yr + base + i4);
  float4 bv = *(const float4*)(bias + i4);
  float4 u;
  u.x = xv.x + yv.x + bv.x; u.y = xv.y + yv.y + bv.y;
  u.z = xv.z + yv.z + bv.z; u.w = xv.w + yv.w + bv.w;

  float s = u.x + u.y + u.z + u.w;
#pragma unroll
  for (int o = 32; o > 0; o >>= 1) s += __shfl_down(s, o);
  if (lnn == 0) sbuf[wv] = s;
  __syncthreads();
  float mean = (sbuf[0] + sbuf[1] + sbuf[2]) * (1.0f / En);

  float4 dv;
  dv.x = u.x - mean; dv.y = u.y - mean; dv.z = u.z - mean; dv.w = u.w - mean;
  float s2 = dv.x * dv.x + dv.y * dv.y + dv.z * dv.z + dv.w * dv.w;
#pragma unroll
  for (int o = 32; o > 0; o >>= 1) s2 += __shfl_down(s2, o);
  __syncthreads();  // protect sbuf reuse
  if (lnn == 0) sbuf[wv] = s2;
  __syncthreads();
  float rstd = rsqrtf((sbuf[0] + sbuf[1] + sbuf[2]) * (1.0f / En) + 1e-5f);

  float4 gv = *(const float4*)(g + i4);
  float4 ev = *(const float4*)(be + i4);
  float4 ov;
  ov.x = dv.x * rstd * gv.x + ev.x; ov.y = dv.y * rstd * gv.y + ev.y;
  ov.z = dv.z * rstd * gv.z + ev.z; ov.w = dv.w * rstd * gv.w + ev.w;
  *(float4*)(outf + base + i4) = ov;
  if (outb) {
    short4 ob;
    ob.x = f2bs(ov.x); ob.y = f2bs(ov.y); ob.z = f2bs(ov.z); ob.w = f2bs(ov.w);
    *(short4*)(outb + base + i4) = ob;
  }
}

// ---------------- launch ----------------
extern "C" void kernel_launch(void* const* d_in, const int* in_sizes, int n_in,
                              void* d_out, int out_size, void* d_ws, size_t ws_size,
                              hipStream_t stream) {
  const float* x   = (const float*)d_in[0];
  const float* Wq  = (const float*)d_in[2];
  const float* bq  = (const float*)d_in[3];
  const float* Wk  = (const float*)d_in[4];
  const float* bk  = (const float*)d_in[5];
  const float* Wv  = (const float*)d_in[6];
  const float* bv  = (const float*)d_in[7];
  const float* Wo  = (const float*)d_in[8];
  const float* bo  = (const float*)d_in[9];
  const float* W1  = (const float*)d_in[10];
  const float* b1  = (const float*)d_in[11];
  const float* W2  = (const float*)d_in[12];
  const float* b2  = (const float*)d_in[13];
  const float* g1  = (const float*)d_in[14];
  const float* be1 = (const float*)d_in[15];
  const float* g2  = (const float*)d_in[16];
  const float* be2 = (const float*)d_in[17];
  float* out = (float*)d_out;
  char* ws = (char*)d_ws;

  // ---- workspace layout (bytes), total 70,778,880 (~67.5 MB) ----
  constexpr size_t OFF_XB    = 0;
  constexpr size_t OFF_WTQKV = 6291456;
  constexpr size_t OFF_VTILE = 6291456;    // overlays dead wt_qkv
  constexpr size_t OFF_WTO   = 9830400;
  constexpr size_t OFF_Q     = 11010048;
  constexpr size_t OFF_K     = 17301504;
  constexpr size_t OFF_VT    = 23592960;
  constexpr size_t OFF_FF1   = 0;          // overlays transient pool
  constexpr size_t OFF_WT1   = 29884416;
  constexpr size_t OFF_WT2   = 34603008;
  constexpr size_t OFF_Y     = 39321600;
  constexpr size_t OFF_X1    = 51904512;
  constexpr size_t OFF_X1B   = 64487424;

  short* xb     = (short*)(ws + OFF_XB);
  short* attb   = (short*)(ws + OFF_XB);
  short* wt_qkv = (short*)(ws + OFF_WTQKV);
  float* vtile  = (float*)(ws + OFF_VTILE);
  short* wt_o   = (short*)(ws + OFF_WTO);
  short* wt_1   = (short*)(ws + OFF_WT1);
  short* wt_2   = (short*)(ws + OFF_WT2);
  short* qb     = (short*)(ws + OFF_Q);
  short* kb     = (short*)(ws + OFF_K);
  short* vt     = (short*)(ws + OFF_VT);
  float* y1     = (float*)(ws + OFF_Y);
  float* y2     = (float*)(ws + OFF_Y);
  float* x1     = (float*)(ws + OFF_X1);
  short* x1b    = (short*)(ws + OFF_X1B);
  short* ff1    = (short*)(ws + OFF_FF1);

  prep_all<<<9984, 256, 0, stream>>>(x, xb, Wq, Wk, Wv, Wo, W1, W2,
                                     wt_qkv, wt_o, wt_1, wt_2);

  gemm_bt<128, 128, 1, 3, 0><<<dim3(18, 32), 256, 0, stream>>>(xb, wt_qkv, Mn, 2304, 768,
      nullptr, nullptr, bq, bk, bv, qb, kb, vt);
  vtile_sum<<<48, 256, 0, stream>>>(vt, vtile);
  attn_kernel<<<dim3(48, 16), 256, 0, stream>>>(qb, kb, vt, vtile, attb);
  gemm_bt<64, 64, 0, 4, 1><<<dim3(12, 64), 256, 0, stream>>>(attb, wt_o, Mn, 768, 768,
      y1, nullptr, nullptr, nullptr, nullptr, nullptr, nullptr, nullptr);
  ln_kernel<<<Mn, 192, 0, stream>>>(x, y1, bo, g1, be1, x1, x1b);
  gemm_bt<128, 128, 2, 3, 0><<<dim3(24, 32), 256, 0, stream>>>(x1b, wt_1, Mn, 3072, 768,
      nullptr, ff1, b1, nullptr, nullptr, nullptr, nullptr, nullptr);
  gemm_bt<64, 64, 0, 4, 1><<<dim3(12, 64), 256, 0, stream>>>(ff1, wt_2, Mn, 768, 3072,
      y2, nullptr, nullptr, nullptr, nullptr, nullptr, nullptr, nullptr);
  ln_kernel<<<Mn, 192, 0, stream>>>(x1, y2, b2, g2, be2, out, nullptr);
}